// Round 8
// baseline (3806.643 us; speedup 1.0000x reference)
//
#include <hip/hip_runtime.h>
#include <math.h>

// ASMambaBlock: router + 4-direction Mamba (selective scan) + windowed MHA.
// All tensors float32. Internal f32 in d_ws. Batch-sliced: per-slice floats =
// 4096 + R*4376, R = BS*1024, BS = largest of {8,4,2,1} fitting ws_size.

#define NSEQ  1024
#define DMODEL 384
#define DINNER 768
#define DSTATE 64
#define XW 152            // dt_rank(24) + 2*d_state(128)

// PERMS closed-form: side=32. p1 = 32x32 transpose, p2/p3 = reversals.
template<int DIR>
__device__ __forceinline__ int permi(int i){
  if (DIR == 0) return i;
  if (DIR == 1) return ((i & 31) << 5) | (i >> 5);
  if (DIR == 2) return 1023 - i;
  int j = 1023 - i; return ((j & 31) << 5) | (j >> 5);
}

// ---------------- router ----------------
__global__ __launch_bounds__(384) void router_mean_kernel(const float* __restrict__ X, float* __restrict__ G){
  int b = blockIdx.y, chunk = blockIdx.x, c = threadIdx.x;
  float s = 0.f;
  const float* xp = X + ((size_t)b*NSEQ + (size_t)chunk*64)*DMODEL + c;
  for (int l = 0; l < 64; ++l) s += xp[(size_t)l*DMODEL];
  atomicAdd(&G[b*DMODEL + c], s * (1.f/1024.f));
}

__global__ __launch_bounds__(96) void router_mlp_kernel(const float* __restrict__ G,
    const float* __restrict__ w1, const float* __restrict__ b1,
    const float* __restrict__ w2, const float* __restrict__ b2, float* __restrict__ WR){
  int b = blockIdx.x, j = threadIdx.x;
  __shared__ float hs[96];
  __shared__ float ls[4];
  float a = b1[j];
  const float* g = G + b*DMODEL;
  for (int c = 0; c < DMODEL; ++c) a += g[c] * w1[j*DMODEL + c];
  hs[j] = 0.5f * a * (1.f + erff(a * 0.70710678118654752f));  // exact gelu
  __syncthreads();
  if (j < 4) {
    float lg = b2[j];
    for (int jj = 0; jj < 96; ++jj) lg += hs[jj] * w2[j*96 + jj];
    ls[j] = lg;
  }
  __syncthreads();
  if (j == 0) {
    float mx = fmaxf(fmaxf(ls[0],ls[1]),fmaxf(ls[2],ls[3]));
    float e0=__expf(ls[0]-mx), e1=__expf(ls[1]-mx), e2=__expf(ls[2]-mx), e3=__expf(ls[3]-mx);
    float s = e0+e1+e2+e3;
    WR[b*4+0]=e0/s; WR[b*4+1]=e1/s; WR[b*4+2]=e2/s; WR[b*4+3]=e3/s;
  }
}

// ---------------- layernorm family (wave64 per 384-row) ----------------
__global__ __launch_bounds__(256) void ln_kernel(const float* __restrict__ X,
    const float* __restrict__ w, const float* __restrict__ bb, float* __restrict__ O){
  int row = blockIdx.x*4 + (threadIdx.x >> 6);
  int lane = threadIdx.x & 63;
  const float* xr = X + (size_t)row*DMODEL;
  float v[6]; float s=0.f, s2=0.f;
  #pragma unroll
  for (int j=0;j<6;++j){ float t = xr[lane + j*64]; v[j]=t; s+=t; s2+=t*t; }
  #pragma unroll
  for (int m=1;m<64;m<<=1){ s += __shfl_xor(s,m,64); s2 += __shfl_xor(s2,m,64); }
  float mu = s*(1.f/DMODEL);
  float rs = rsqrtf(s2*(1.f/DMODEL) - mu*mu + 1e-5f);
  float* o = O + (size_t)row*DMODEL;
  #pragma unroll
  for (int j=0;j<6;++j){ int i = lane+j*64; o[i] = (v[j]-mu)*rs*w[i] + bb[i]; }
}

__global__ __launch_bounds__(256) void ln_final_kernel(const float* __restrict__ XN2,
    const float* __restrict__ AO, const float* __restrict__ gatep,
    const float* __restrict__ w, const float* __restrict__ bb, float* __restrict__ OUT){
  int row = blockIdx.x*4 + (threadIdx.x >> 6);
  int lane = threadIdx.x & 63;
  float gate = gatep[0];
  const float* xr = XN2 + (size_t)row*DMODEL;
  const float* ar = AO + (size_t)row*DMODEL;
  float v[6]; float s=0.f, s2=0.f;
  #pragma unroll
  for (int j=0;j<6;++j){ int i = lane+j*64; float t = xr[i] + gate*ar[i]; v[j]=t; s+=t; s2+=t*t; }
  #pragma unroll
  for (int m=1;m<64;m<<=1){ s += __shfl_xor(s,m,64); s2 += __shfl_xor(s2,m,64); }
  float mu = s*(1.f/DMODEL);
  float rs = rsqrtf(s2*(1.f/DMODEL) - mu*mu + 1e-5f);
  float* o = OUT + (size_t)row*DMODEL;
  #pragma unroll
  for (int j=0;j<6;++j){ int i = lane+j*64; o[i] = (v[j]-mu)*rs*w[i] + bb[i]; }
}

// ---------------- generic f32 GEMM: C[m,n] = act(sum_k A[m,k]*W[n,k] + bias[n]) + resid ----------------
#define GBM 128
#define GBN 128
#define GBK 8
__global__ __launch_bounds__(256) void gemm_kernel(
    const float* __restrict__ A, int lda,
    const float* __restrict__ W, int K, int N,
    const float* __restrict__ bias,
    const float* __restrict__ resid,   // f32 [M x ldc]
    int act,                           // 0 none, 1 softplus
    float* __restrict__ C, int ldc)
{
  __shared__ float As[GBK][GBM+4];
  __shared__ float Ws[GBK][GBN+4];
  const int t = threadIdx.x;
  const int m0 = blockIdx.y * GBM;
  const int n0 = blockIdx.x * GBN;
  const int tx = t & 15, ty = t >> 4;
  const int lrow = t >> 1;
  const int lkq  = (t & 1)*4;
  float acc[8][8];
  #pragma unroll
  for (int i=0;i<8;++i){
    #pragma unroll
    for (int j=0;j<8;++j) acc[i][j]=0.f;
  }
  for (int k0 = 0; k0 < K; k0 += GBK) {
    float4 av = *(const float4*)(A + (size_t)(m0+lrow)*lda + k0 + lkq);
    float4 wv = {0.f,0.f,0.f,0.f};
    {
      int n = n0 + lrow;
      if (n < N) wv = *(const float4*)(W + (size_t)n*K + k0 + lkq);
    }
    __syncthreads();
    As[lkq+0][lrow]=av.x; As[lkq+1][lrow]=av.y; As[lkq+2][lrow]=av.z; As[lkq+3][lrow]=av.w;
    Ws[lkq+0][lrow]=wv.x; Ws[lkq+1][lrow]=wv.y; Ws[lkq+2][lrow]=wv.z; Ws[lkq+3][lrow]=wv.w;
    __syncthreads();
    #pragma unroll
    for (int kk=0;kk<GBK;++kk){
      float4 a0 = *(const float4*)&As[kk][ty*8];
      float4 a1 = *(const float4*)&As[kk][ty*8+4];
      float4 b0 = *(const float4*)&Ws[kk][tx*8];
      float4 b1 = *(const float4*)&Ws[kk][tx*8+4];
      float a[8]={a0.x,a0.y,a0.z,a0.w,a1.x,a1.y,a1.z,a1.w};
      float bb[8]={b0.x,b0.y,b0.z,b0.w,b1.x,b1.y,b1.z,b1.w};
      #pragma unroll
      for (int i=0;i<8;++i){
        #pragma unroll
        for (int j=0;j<8;++j) acc[i][j] += a[i]*bb[j];
      }
    }
  }
  #pragma unroll
  for (int i=0;i<8;++i){
    int m = m0 + ty*8 + i;
    #pragma unroll
    for (int j=0;j<8;++j){
      int n = n0 + tx*8 + j;
      if (n < N){
        float v = acc[i][j];
        if (bias)  v += bias[n];
        if (act == 1) v = (v > 20.f) ? v : log1pf(__expf(v));
        if (resid) v += resid[(size_t)m*ldc + n];
        C[(size_t)m*ldc + n] = v;
      }
    }
  }
}

// ---------------- in-place silu on the z-half of XZ (once, shared by 4 dirs) ----------------
__global__ __launch_bounds__(256) void zsilu_kernel(float* __restrict__ XZ){
  int idx = blockIdx.x*256 + threadIdx.x;       // R*192 threads, float4 each
  int row = idx / 192, q = idx % 192;
  float4* p = (float4*)(XZ + (size_t)row*1536 + DINNER + q*4);
  float4 v = *p;
  v.x = v.x / (1.f + __expf(-v.x));
  v.y = v.y / (1.f + __expf(-v.y));
  v.z = v.z / (1.f + __expf(-v.z));
  v.w = v.w / (1.f + __expf(-v.w));
  *p = v;
}

// ---------------- depthwise causal conv (k=4) over permuted sequence + silu ----------------
template<int DIR>
__global__ __launch_bounds__(256) void conv_silu_kernel(const float* __restrict__ XZ,
    const float* __restrict__ cw, const float* __restrict__ cb, float* __restrict__ Uo){
  int idx = blockIdx.x*256 + threadIdx.x;        // (local b)*1024*768 + i*768 + c
  int c = idx % DINNER;
  int rest = idx / DINNER;
  int i = rest & 1023;
  int b = rest >> 10;
  float acc = cb[c];
  #pragma unroll
  for (int k = 0; k < 4; ++k) {
    int ii = i - 3 + k;
    if (ii >= 0)
      acc += cw[c*4 + k] * XZ[((size_t)b*NSEQ + permi<DIR>(ii))*1536 + c];
  }
  Uo[idx] = acc / (1.f + __expf(-acc));          // silu
}

// ---------------- selective scan ----------------
// All-DPP wave64 reduce: 4x row_ror (row sums) + row_bcast15 + row_bcast31.
template<int CTRL>
__device__ __forceinline__ float dpp_add(float v){
  int t = __builtin_amdgcn_update_dpp(0, __float_as_int(v), CTRL, 0xf, 0xf, true);
  return v + __int_as_float(t);
}
__device__ __forceinline__ float wave64_reduce_hi(float p){
  p = dpp_add<0x128>(p); // row_ror 8
  p = dpp_add<0x124>(p); // row_ror 4
  p = dpp_add<0x122>(p); // row_ror 2
  p = dpp_add<0x121>(p); // row_ror 1  -> each row of 16 has its sum
  p = dpp_add<0x142>(p); // row_bcast15: row1 += row0, row3 += row2
  p = dpp_add<0x143>(p); // row_bcast31: lanes32-63 += (row0+row1)
  return p;              // lanes 48..63 = total
}

// Block = 512 threads (8 waves) = 16 consecutive channels: every 64B line of
// DT/U/z/SACC fully consumed within one block. Wave handles 2 channels
// (lane = state) -> 3072 waves = 3 waves/SIMD (2x round-7 TLP, ~half the
// per-step instructions). DIR==0 writes SACC (no memset, no S-read).
template<int DIR>
__global__ __launch_bounds__(512) void scan_kernel(
    const float* __restrict__ XDBL, const float* __restrict__ DT,
    const float* __restrict__ U, const float* __restrict__ XZ,  // z-half pre-silu'd
    const float* __restrict__ A_log, const float* __restrict__ Dskip,
    const float* __restrict__ WR, float* __restrict__ SACC, int b0)
{
  const int b = blockIdx.y;
  const int lane = threadIdx.x & 63;
  const int wave = threadIdx.x >> 6;
  const int c0 = blockIdx.x*16 + wave*2;          // channels c0, c0+1
  const float As0 = -__expf(A_log[(c0+0)*DSTATE + lane]);
  const float As1 = -__expf(A_log[(c0+1)*DSTATE + lane]);
  const float2 dsk = *(const float2*)(Dskip + c0);
  const float wgt = WR[(b0 + b)*4 + DIR];
  const size_t rb = (size_t)b * NSEQ;
  const float* xd  = XDBL + rb*XW;
  const float* dtp = DT + rb*DINNER + c0;
  const float* up  = U  + rb*DINNER + c0;
  const float* zp  = XZ + rb*1536 + DINNER + c0;  // + perm(l)*1536
  float* sp = SACC + rb*DINNER + c0;

#define SLOAD(k, l) { int lr = (l) < 1023 ? (l) : 1023;                     \
    const float* x2 = xd + (size_t)lr*XW;                                   \
    B##k = x2[24+lane]; C##k = x2[88+lane];                                 \
    t##k = *(const float2*)(dtp + (size_t)lr*DINNER);                       \
    v##k = *(const float2*)(up  + (size_t)lr*DINNER);                       \
    w##k = *(const float2*)(zp  + (size_t)permi<DIR>(lr)*1536);             \
    if (DIR != 0) S##k = *(const float2*)(sp + (size_t)lr*DINNER); }

#define SSTEP(k, l) {                                                       \
    float e0 = __expf(t##k.x*As0);                                          \
    float e1 = __expf(t##k.y*As1);                                          \
    g0 = e0*g0 + (t##k.x*v##k.x)*B##k;                                      \
    g1 = e1*g1 + (t##k.y*v##k.y)*B##k;                                      \
    float p0 = wave64_reduce_hi(g0*C##k);                                   \
    float p1 = wave64_reduce_hi(g1*C##k);                                   \
    if (lane == 63) {                                                       \
      float2 o;                                                             \
      float a0 = wgt*(p0 + v##k.x*dsk.x)*w##k.x;                            \
      float a1 = wgt*(p1 + v##k.y*dsk.y)*w##k.y;                            \
      if (DIR == 0) { o.x = a0; o.y = a1; }                                 \
      else { o.x = S##k.x + a0; o.y = S##k.y + a1; }                        \
      *(float2*)(sp + (size_t)(l)*DINNER) = o; } }

  float B0,C0,B1,C1,B2,C2,B3,C3;
  float2 t0,t1,t2,t3, v0,v1,v2,v3, w0,w1,w2,w3;
  float2 S0={0.f,0.f},S1={0.f,0.f},S2={0.f,0.f},S3={0.f,0.f};
  float g0=0.f, g1=0.f;
  SLOAD(0,0) SLOAD(1,1) SLOAD(2,2) SLOAD(3,3)
  __builtin_amdgcn_sched_barrier(0);
  for (int l = 0; l < NSEQ; l += 4) {
    SSTEP(0,l)   SLOAD(0,l+4) __builtin_amdgcn_sched_barrier(0);
    SSTEP(1,l+1) SLOAD(1,l+5) __builtin_amdgcn_sched_barrier(0);
    SSTEP(2,l+2) SLOAD(2,l+6) __builtin_amdgcn_sched_barrier(0);
    SSTEP(3,l+3) SLOAD(3,l+7) __builtin_amdgcn_sched_barrier(0);
  }
#undef SLOAD
#undef SSTEP
}

// ---------------- windowed attention (W=4, heads=4, hd=96) ----------------
__global__ __launch_bounds__(256) void attn_kernel(const float* __restrict__ QKV, float* __restrict__ O){
  int idx = blockIdx.x*256 + threadIdx.x;        // (R/4 windows)*4 heads*4 q = 4R threads
  int tq = idx & 3, h = (idx >> 2) & 3, w = idx >> 4;
  size_t row0 = (size_t)w * 4;
  const float4* qp = (const float4*)(QKV + (row0 + tq)*1152 + h*96);
  float sc[4];
  #pragma unroll
  for (int tk = 0; tk < 4; ++tk) {
    const float4* kp = (const float4*)(QKV + (row0 + tk)*1152 + 384 + h*96);
    float d = 0.f;
    #pragma unroll
    for (int j = 0; j < 24; ++j) {
      float4 qf = qp[j], kf = kp[j];
      d += qf.x*kf.x + qf.y*kf.y + qf.z*kf.z + qf.w*kf.w;
    }
    sc[tk] = d * 0.10206207261596575f;           // 1/sqrt(96)
  }
  float mx = fmaxf(fmaxf(sc[0],sc[1]),fmaxf(sc[2],sc[3]));
  float s = 0.f;
  #pragma unroll
  for (int tk=0;tk<4;++tk){ sc[tk]=__expf(sc[tk]-mx); s+=sc[tk]; }
  float inv = 1.f/s;
  #pragma unroll
  for (int tk=0;tk<4;++tk) sc[tk]*=inv;
  float4* op = (float4*)(O + (row0 + tq)*DMODEL + h*96);
  #pragma unroll 4
  for (int j = 0; j < 24; ++j) {
    float4 o = {0.f,0.f,0.f,0.f};
    #pragma unroll
    for (int tk=0;tk<4;++tk){
      const float4* vp = (const float4*)(QKV + (row0+tk)*1152 + 768 + h*96);
      float4 vf = vp[j];
      o.x += sc[tk]*vf.x; o.y += sc[tk]*vf.y; o.z += sc[tk]*vf.z; o.w += sc[tk]*vf.w;
    }
    op[j] = o;
  }
}

extern "C" void kernel_launch(void* const* d_in, const int* in_sizes, int n_in,
                              void* d_out, int out_size, void* d_ws, size_t ws_size,
                              hipStream_t stream)
{
  (void)in_sizes; (void)n_in; (void)out_size;
  const float* x         = (const float*)d_in[0];
  const float* r_w1      = (const float*)d_in[1];
  const float* r_b1      = (const float*)d_in[2];
  const float* r_w2      = (const float*)d_in[3];
  const float* r_b2      = (const float*)d_in[4];
  const float* ln1_w     = (const float*)d_in[5];
  const float* ln1_b     = (const float*)d_in[6];
  const float* ln2_w     = (const float*)d_in[7];
  const float* ln2_b     = (const float*)d_in[8];
  const float* in_proj_w = (const float*)d_in[9];
  const float* conv_w    = (const float*)d_in[10];
  const float* conv_b    = (const float*)d_in[11];
  const float* x_proj_w  = (const float*)d_in[12];
  const float* dt_proj_w = (const float*)d_in[13];
  const float* dt_proj_b = (const float*)d_in[14];
  const float* A_log     = (const float*)d_in[15];
  const float* D_skip    = (const float*)d_in[16];
  const float* out_proj_w= (const float*)d_in[17];
  const float* qkv_w     = (const float*)d_in[18];
  const float* qkv_b     = (const float*)d_in[19];
  const float* ao_w      = (const float*)d_in[20];
  const float* ao_b      = (const float*)d_in[21];
  const float* gate      = (const float*)d_in[22];
  const float* lng_w     = (const float*)d_in[23];
  const float* lng_b     = (const float*)d_in[24];

  float* ws = (float*)d_ws;
  float* WR = ws;            // 32 floats
  float* G  = ws + 64;       // 3072 floats

  int BS = 8;
  while (BS > 1) {
    size_t need = ((size_t)4096 + (size_t)BS*1024*4376) * sizeof(float);
    if (need <= ws_size) break;
    BS >>= 1;
  }
  const int R = BS * 1024;   // rows per slice

  (void)hipMemsetAsync(ws, 0, 4096*sizeof(float), stream);      // WR + G
  router_mean_kernel<<<dim3(16,8),384,0,stream>>>(x, G);
  router_mlp_kernel<<<8,96,0,stream>>>(G, r_w1, r_b1, r_w2, r_b2, WR);

  float* base = ws + 4096;
  float* XN   = base;                 // R*384
  float* XZ   = XN   + (size_t)R*384; // R*1536
  float* Ub   = XZ   + (size_t)R*1536;// R*768
  float* XDBL = Ub   + (size_t)R*768; // R*152
  float* DTb  = XDBL + (size_t)R*152; // R*768
  float* SACC = DTb  + (size_t)R*768; // R*768
  float* X2   = XN;    // out_proj output (R*384)
  float* XN2  = SACC;  // ln2 output
  float* QKV  = XZ;    // qkv output (R*1152 <= R*1536)
  float* ATTO = Ub;    // attn output
  float* AOb  = DTb;   // ao output

  for (int s = 0; s < 8/BS; ++s) {
    const int b0 = s * BS;
    const size_t xoff = (size_t)b0 * NSEQ * DMODEL;

    ln_kernel<<<R/4,256,0,stream>>>(x + xoff, ln1_w, ln1_b, XN);
    gemm_kernel<<<dim3(12,R/128),256,0,stream>>>(XN,384, in_proj_w,384,1536, nullptr,nullptr,0, XZ,1536);
    zsilu_kernel<<<(R*192)/256,256,0,stream>>>(XZ);   // silu(z) once, in place
    for (int dir = 0; dir < 4; ++dir) {
      switch (dir) {
        case 0: conv_silu_kernel<0><<<3*R,256,0,stream>>>(XZ, conv_w, conv_b, Ub); break;
        case 1: conv_silu_kernel<1><<<3*R,256,0,stream>>>(XZ, conv_w, conv_b, Ub); break;
        case 2: conv_silu_kernel<2><<<3*R,256,0,stream>>>(XZ, conv_w, conv_b, Ub); break;
        default: conv_silu_kernel<3><<<3*R,256,0,stream>>>(XZ, conv_w, conv_b, Ub); break;
      }
      gemm_kernel<<<dim3(2,R/128),256,0,stream>>>(Ub,768, x_proj_w,768,152, nullptr,nullptr,0, XDBL,152);
      gemm_kernel<<<dim3(6,R/128),256,0,stream>>>(XDBL,152, dt_proj_w,24,768, dt_proj_b,nullptr,1, DTb,768);
      switch (dir) {
        case 0: scan_kernel<0><<<dim3(48,BS),512,0,stream>>>(XDBL, DTb, Ub, XZ, A_log, D_skip, WR, SACC, b0); break;
        case 1: scan_kernel<1><<<dim3(48,BS),512,0,stream>>>(XDBL, DTb, Ub, XZ, A_log, D_skip, WR, SACC, b0); break;
        case 2: scan_kernel<2><<<dim3(48,BS),512,0,stream>>>(XDBL, DTb, Ub, XZ, A_log, D_skip, WR, SACC, b0); break;
        default: scan_kernel<3><<<dim3(48,BS),512,0,stream>>>(XDBL, DTb, Ub, XZ, A_log, D_skip, WR, SACC, b0); break;
      }
    }
    gemm_kernel<<<dim3(3,R/128),256,0,stream>>>(SACC,768, out_proj_w,768,384, nullptr,x + xoff,0, X2,384);
    ln_kernel<<<R/4,256,0,stream>>>(X2, ln2_w, ln2_b, XN2);
    gemm_kernel<<<dim3(9,R/128),256,0,stream>>>(XN2,384, qkv_w,384,1152, qkv_b,nullptr,0, QKV,1152);
    attn_kernel<<<R/64,256,0,stream>>>(QKV, ATTO);
    gemm_kernel<<<dim3(3,R/128),256,0,stream>>>(ATTO,384, ao_w,384,384, ao_b,nullptr,0, AOb,384);
    ln_final_kernel<<<R/4,256,0,stream>>>(XN2, AOb, gate, lng_w, lng_b, (float*)d_out + xoff);
  }
}

// Round 9
// 2128.209 us; speedup vs baseline: 1.7887x; 1.7887x over previous
//
#include <hip/hip_runtime.h>
#include <math.h>

// ASMambaBlock: router + 4-dir Mamba (selective scan) + windowed MHA.
// f32 tensors; GEMMs run on bf16 MFMA (m97-verified fragment layouts).
// ws (floats): WR 0 | G 64 | WBF(bf16 weights, 804864 fl) @3200 | slices @808064.
// Per-slice: ABF R*384 | XZ R*1536 | Ub(bf16) R*384 | XDBL R*152 | DTb(bf16) R*384
// | SACC R*768  = R*3608 floats. R=8192 -> 121.5 MB total (< round-3-proven 143.4).

#define NSEQ  1024
#define DMODEL 384
#define DINNER 768
#define DSTATE 64
#define XW 152

typedef unsigned short u16;
typedef __attribute__((ext_vector_type(8))) short short8;
typedef __attribute__((ext_vector_type(4))) float f32x4;

__device__ __forceinline__ float bf2f(u16 u){
  union { unsigned int i; float f; } c; c.i = ((unsigned int)u) << 16; return c.f;
}
__device__ __forceinline__ u16 f2bf(float f){
  union { float f; unsigned int i; } c; c.f = f;
  unsigned int x = c.i;
  return (u16)((x + 0x7fffu + ((x >> 16) & 1u)) >> 16);
}

template<int DIR>
__device__ __forceinline__ int permi(int i){
  if (DIR == 0) return i;
  if (DIR == 1) return ((i & 31) << 5) | (i >> 5);
  if (DIR == 2) return 1023 - i;
  int j = 1023 - i; return ((j & 31) << 5) | (j >> 5);
}

// ---------------- router ----------------
__global__ __launch_bounds__(384) void router_mean_kernel(const float* __restrict__ X, float* __restrict__ G){
  int b = blockIdx.y, chunk = blockIdx.x, c = threadIdx.x;
  float s = 0.f;
  const float* xp = X + ((size_t)b*NSEQ + (size_t)chunk*64)*DMODEL + c;
  for (int l = 0; l < 64; ++l) s += xp[(size_t)l*DMODEL];
  atomicAdd(&G[b*DMODEL + c], s * (1.f/1024.f));
}

__global__ __launch_bounds__(96) void router_mlp_kernel(const float* __restrict__ G,
    const float* __restrict__ w1, const float* __restrict__ b1,
    const float* __restrict__ w2, const float* __restrict__ b2, float* __restrict__ WR){
  int b = blockIdx.x, j = threadIdx.x;
  __shared__ float hs[96];
  __shared__ float ls[4];
  float a = b1[j];
  const float* g = G + b*DMODEL;
  for (int c = 0; c < DMODEL; ++c) a += g[c] * w1[j*DMODEL + c];
  hs[j] = 0.5f * a * (1.f + erff(a * 0.70710678118654752f));
  __syncthreads();
  if (j < 4) {
    float lg = b2[j];
    for (int jj = 0; jj < 96; ++jj) lg += hs[jj] * w2[j*96 + jj];
    ls[j] = lg;
  }
  __syncthreads();
  if (j == 0) {
    float mx = fmaxf(fmaxf(ls[0],ls[1]),fmaxf(ls[2],ls[3]));
    float e0=__expf(ls[0]-mx), e1=__expf(ls[1]-mx), e2=__expf(ls[2]-mx), e3=__expf(ls[3]-mx);
    float s = e0+e1+e2+e3;
    WR[b*4+0]=e0/s; WR[b*4+1]=e1/s; WR[b*4+2]=e2/s; WR[b*4+3]=e3/s;
  }
}

// ---------------- layernorms ----------------
__global__ __launch_bounds__(256) void ln_bf16out_kernel(const float* __restrict__ X,
    const float* __restrict__ w, const float* __restrict__ bb, u16* __restrict__ O){
  int row = blockIdx.x*4 + (threadIdx.x >> 6);
  int lane = threadIdx.x & 63;
  const float* xr = X + (size_t)row*DMODEL;
  float v[6]; float s=0.f, s2=0.f;
  #pragma unroll
  for (int j=0;j<6;++j){ float t = xr[lane + j*64]; v[j]=t; s+=t; s2+=t*t; }
  #pragma unroll
  for (int m=1;m<64;m<<=1){ s += __shfl_xor(s,m,64); s2 += __shfl_xor(s2,m,64); }
  float mu = s*(1.f/DMODEL);
  float rs = rsqrtf(s2*(1.f/DMODEL) - mu*mu + 1e-5f);
  u16* o = O + (size_t)row*DMODEL;
  #pragma unroll
  for (int j=0;j<6;++j){ int i = lane+j*64; o[i] = f2bf((v[j]-mu)*rs*w[i] + bb[i]); }
}

__global__ __launch_bounds__(256) void ln_kernel(const float* __restrict__ X,
    const float* __restrict__ w, const float* __restrict__ bb, float* __restrict__ O){
  int row = blockIdx.x*4 + (threadIdx.x >> 6);
  int lane = threadIdx.x & 63;
  const float* xr = X + (size_t)row*DMODEL;
  float v[6]; float s=0.f, s2=0.f;
  #pragma unroll
  for (int j=0;j<6;++j){ float t = xr[lane + j*64]; v[j]=t; s+=t; s2+=t*t; }
  #pragma unroll
  for (int m=1;m<64;m<<=1){ s += __shfl_xor(s,m,64); s2 += __shfl_xor(s2,m,64); }
  float mu = s*(1.f/DMODEL);
  float rs = rsqrtf(s2*(1.f/DMODEL) - mu*mu + 1e-5f);
  float* o = O + (size_t)row*DMODEL;
  #pragma unroll
  for (int j=0;j<6;++j){ int i = lane+j*64; o[i] = (v[j]-mu)*rs*w[i] + bb[i]; }
}

__global__ __launch_bounds__(256) void ln_final_kernel(const float* __restrict__ XN2,
    const float* __restrict__ AO, const float* __restrict__ gatep,
    const float* __restrict__ w, const float* __restrict__ bb, float* __restrict__ OUT){
  int row = blockIdx.x*4 + (threadIdx.x >> 6);
  int lane = threadIdx.x & 63;
  float gate = gatep[0];
  const float* xr = XN2 + (size_t)row*DMODEL;
  const float* ar = AO + (size_t)row*DMODEL;
  float v[6]; float s=0.f, s2=0.f;
  #pragma unroll
  for (int j=0;j<6;++j){ int i = lane+j*64; float t = xr[i] + gate*ar[i]; v[j]=t; s+=t; s2+=t*t; }
  #pragma unroll
  for (int m=1;m<64;m<<=1){ s += __shfl_xor(s,m,64); s2 += __shfl_xor(s2,m,64); }
  float mu = s*(1.f/DMODEL);
  float rs = rsqrtf(s2*(1.f/DMODEL) - mu*mu + 1e-5f);
  float* o = OUT + (size_t)row*DMODEL;
  #pragma unroll
  for (int j=0;j<6;++j){ int i = lane+j*64; o[i] = (v[j]-mu)*rs*w[i] + bb[i]; }
}

// ---------------- f32 -> bf16 conversion (vectorized) ----------------
__global__ __launch_bounds__(256) void cvt4_kernel(const float* __restrict__ src,
    u16* __restrict__ dst, int n4){
  int i = blockIdx.x*256 + threadIdx.x;
  if (i >= n4) return;
  float4 v = ((const float4*)src)[i];
  ushort4 o; o.x=f2bf(v.x); o.y=f2bf(v.y); o.z=f2bf(v.z); o.w=f2bf(v.w);
  ((ushort4*)dst)[i] = o;
}

// ---------------- bf16 MFMA GEMM: C[m,n] = act(A@W^T + bias) (+resid) ----------------
// A bf16 [M][lda], W bf16 [N][K]. Wave owns 64x64 output; no LDS (W L2-resident).
// Frag layouts (m89/m97-verified): A lane: row=l%16, k=k0+(l>>4)*8+j (8 contiguous).
// C/D: col=lane&15, row=(lane>>4)*4+reg.
__global__ __launch_bounds__(256) void mgemm_kernel(
    const u16* __restrict__ A, int lda,
    const u16* __restrict__ W, int K, int N,
    const float* __restrict__ bias,
    const float* __restrict__ resid,
    int act,                 // 0 none, 1 softplus
    int obf,                 // 0: f32 out, 1: bf16 out
    void* __restrict__ C, int ldc)
{
  const int lane = threadIdx.x & 63;
  const int wv = threadIdx.x >> 6;
  const int m0 = (blockIdx.y*4 + wv) * 64;
  const int n0 = blockIdx.x * 64;
  const int r  = lane & 15;
  const int kg = lane >> 4;
  f32x4 acc[4][4];
  #pragma unroll
  for (int i=0;i<4;++i){
    #pragma unroll
    for (int j=0;j<4;++j) acc[i][j] = (f32x4)0.f;
  }
  for (int k0 = 0; k0 < K; k0 += 32) {
    const bool kval = (k0 + kg*8) < K;     // K%8==0 so 8-run all-valid or all-invalid
    short8 a[4], b[4];
    #pragma unroll
    for (int i = 0; i < 4; ++i) {
      a[i] = kval ? *(const short8*)(A + (size_t)(m0 + i*16 + r)*lda + k0 + kg*8) : (short8)0;
      int n = n0 + i*16 + r;
      b[i] = (kval && n < N) ? *(const short8*)(W + (size_t)n*K + k0 + kg*8) : (short8)0;
    }
    #pragma unroll
    for (int ai = 0; ai < 4; ++ai)
      #pragma unroll
      for (int bi = 0; bi < 4; ++bi)
        acc[ai][bi] = __builtin_amdgcn_mfma_f32_16x16x32_bf16(a[ai], b[bi], acc[ai][bi], 0, 0, 0);
  }
  #pragma unroll
  for (int ai = 0; ai < 4; ++ai) {
    int mrow = m0 + ai*16 + kg*4;
    #pragma unroll
    for (int bi = 0; bi < 4; ++bi) {
      int n = n0 + bi*16 + r;
      if (n < N) {
        #pragma unroll
        for (int q = 0; q < 4; ++q) {
          float v = acc[ai][bi][q];
          int m = mrow + q;
          if (bias) v += bias[n];
          if (act == 1) v = (v > 20.f) ? v : log1pf(__expf(v));
          if (resid) v += resid[(size_t)m*ldc + n];
          if (obf) ((u16*)C)[(size_t)m*ldc + n] = f2bf(v);
          else     ((float*)C)[(size_t)m*ldc + n] = v;
        }
      }
    }
  }
}

// ---------------- in-place silu on z-half of XZ ----------------
__global__ __launch_bounds__(256) void zsilu_kernel(float* __restrict__ XZ){
  int idx = blockIdx.x*256 + threadIdx.x;
  int row = idx / 192, q = idx % 192;
  float4* p = (float4*)(XZ + (size_t)row*1536 + DINNER + q*4);
  float4 v = *p;
  v.x = v.x / (1.f + __expf(-v.x));
  v.y = v.y / (1.f + __expf(-v.y));
  v.z = v.z / (1.f + __expf(-v.z));
  v.w = v.w / (1.f + __expf(-v.w));
  *p = v;
}

// ---------------- depthwise causal conv (k=4) + silu -> bf16 ----------------
template<int DIR>
__global__ __launch_bounds__(256) void conv_silu_kernel(const float* __restrict__ XZ,
    const float* __restrict__ cw, const float* __restrict__ cb, u16* __restrict__ Uo){
  int idx = blockIdx.x*256 + threadIdx.x;
  int c = idx % DINNER;
  int rest = idx / DINNER;
  int i = rest & 1023;
  int b = rest >> 10;
  float acc = cb[c];
  #pragma unroll
  for (int k = 0; k < 4; ++k) {
    int ii = i - 3 + k;
    if (ii >= 0)
      acc += cw[c*4 + k] * XZ[((size_t)b*NSEQ + permi<DIR>(ii))*1536 + c];
  }
  Uo[idx] = f2bf(acc / (1.f + __expf(-acc)));
}

// ---------------- selective scan (round-7 shape: 4 ch/wave, 16 ch/block) ----------------
template<int CTRL>
__device__ __forceinline__ float dpp_add(float v){
  int t = __builtin_amdgcn_update_dpp(0, __float_as_int(v), CTRL, 0xf, 0xf, true);
  return v + __int_as_float(t);
}
__device__ __forceinline__ float wave64_reduce_hi(float p){
  p = dpp_add<0x128>(p);
  p = dpp_add<0x124>(p);
  p = dpp_add<0x122>(p);
  p = dpp_add<0x121>(p);
  p = dpp_add<0x142>(p);
  p = dpp_add<0x143>(p);
  return p;              // lanes 48..63 = total
}

template<int DIR>
__global__ __launch_bounds__(256) void scan_kernel(
    const float* __restrict__ XDBL, const u16* __restrict__ DT,
    const u16* __restrict__ U, const float* __restrict__ XZ,
    const float* __restrict__ A_log, const float* __restrict__ Dskip,
    const float* __restrict__ WR, float* __restrict__ SACC, int b0)
{
  const int b = blockIdx.y;
  const int lane = threadIdx.x & 63;
  const int wave = threadIdx.x >> 6;
  const int c0 = blockIdx.x*16 + wave*4;
  const float As0 = -__expf(A_log[(c0+0)*DSTATE + lane]);
  const float As1 = -__expf(A_log[(c0+1)*DSTATE + lane]);
  const float As2 = -__expf(A_log[(c0+2)*DSTATE + lane]);
  const float As3 = -__expf(A_log[(c0+3)*DSTATE + lane]);
  const float4 dsk = *(const float4*)(Dskip + c0);
  const float wgt = WR[(b0 + b)*4 + DIR];
  const size_t rb = (size_t)b * NSEQ;
  const float* xd  = XDBL + rb*XW;
  const u16* dtp = DT + rb*DINNER + c0;
  const u16* up  = U  + rb*DINNER + c0;
  const float* zp  = XZ + rb*1536 + DINNER + c0;
  float* sp = SACC + rb*DINNER + c0;

#define SLOAD(k, l) { int lr = (l) < 1023 ? (l) : 1023;                     \
    const float* x2 = xd + (size_t)lr*XW;                                   \
    B##k = x2[24+lane]; C##k = x2[88+lane];                                 \
    uint2 td = *(const uint2*)(dtp + (size_t)lr*DINNER);                    \
    uint2 ud = *(const uint2*)(up  + (size_t)lr*DINNER);                    \
    t##k.x = bf2f(td.x & 0xffffu); t##k.y = bf2f(td.x >> 16);               \
    t##k.z = bf2f(td.y & 0xffffu); t##k.w = bf2f(td.y >> 16);               \
    v##k.x = bf2f(ud.x & 0xffffu); v##k.y = bf2f(ud.x >> 16);               \
    v##k.z = bf2f(ud.y & 0xffffu); v##k.w = bf2f(ud.y >> 16);               \
    w##k = *(const float4*)(zp + (size_t)permi<DIR>(lr)*1536);              \
    if (DIR != 0) S##k = *(const float4*)(sp + (size_t)lr*DINNER); }

#define SSTEP(k, l) {                                                       \
    float e;                                                                \
    e = __expf(t##k.x*As0); g0 = e*g0 + (t##k.x*v##k.x)*B##k;               \
    e = __expf(t##k.y*As1); g1 = e*g1 + (t##k.y*v##k.y)*B##k;               \
    e = __expf(t##k.z*As2); g2 = e*g2 + (t##k.z*v##k.z)*B##k;               \
    e = __expf(t##k.w*As3); g3 = e*g3 + (t##k.w*v##k.w)*B##k;               \
    float p0 = wave64_reduce_hi(g0*C##k);                                   \
    float p1 = wave64_reduce_hi(g1*C##k);                                   \
    float p2 = wave64_reduce_hi(g2*C##k);                                   \
    float p3 = wave64_reduce_hi(g3*C##k);                                   \
    if (lane == 63) {                                                       \
      float4 o;                                                             \
      float a0 = wgt*(p0 + v##k.x*dsk.x)*w##k.x;                            \
      float a1 = wgt*(p1 + v##k.y*dsk.y)*w##k.y;                            \
      float a2 = wgt*(p2 + v##k.z*dsk.z)*w##k.z;                            \
      float a3 = wgt*(p3 + v##k.w*dsk.w)*w##k.w;                            \
      if (DIR == 0) { o.x=a0; o.y=a1; o.z=a2; o.w=a3; }                     \
      else { o.x=S##k.x+a0; o.y=S##k.y+a1; o.z=S##k.z+a2; o.w=S##k.w+a3; }  \
      *(float4*)(sp + (size_t)(l)*DINNER) = o; } }

  float B0,C0,B1,C1,B2,C2,B3,C3;
  float4 t0,t1,t2,t3, v0,v1,v2,v3, w0,w1,w2,w3;
  float4 S0={0.f,0.f,0.f,0.f},S1=S0,S2=S0,S3=S0;
  float g0=0.f, g1=0.f, g2=0.f, g3=0.f;
  SLOAD(0,0) SLOAD(1,1) SLOAD(2,2) SLOAD(3,3)
  __builtin_amdgcn_sched_barrier(0);
  for (int l = 0; l < NSEQ; l += 4) {
    SSTEP(0,l)   SLOAD(0,l+4) __builtin_amdgcn_sched_barrier(0);
    SSTEP(1,l+1) SLOAD(1,l+5) __builtin_amdgcn_sched_barrier(0);
    SSTEP(2,l+2) SLOAD(2,l+6) __builtin_amdgcn_sched_barrier(0);
    SSTEP(3,l+3) SLOAD(3,l+7) __builtin_amdgcn_sched_barrier(0);
  }
#undef SLOAD
#undef SSTEP
}

// ---------------- windowed attention ----------------
__global__ __launch_bounds__(256) void attn_kernel(const float* __restrict__ QKV, float* __restrict__ O){
  int idx = blockIdx.x*256 + threadIdx.x;
  int tq = idx & 3, h = (idx >> 2) & 3, w = idx >> 4;
  size_t row0 = (size_t)w * 4;
  const float4* qp = (const float4*)(QKV + (row0 + tq)*1152 + h*96);
  float sc[4];
  #pragma unroll
  for (int tk = 0; tk < 4; ++tk) {
    const float4* kp = (const float4*)(QKV + (row0 + tk)*1152 + 384 + h*96);
    float d = 0.f;
    #pragma unroll
    for (int j = 0; j < 24; ++j) {
      float4 qf = qp[j], kf = kp[j];
      d += qf.x*kf.x + qf.y*kf.y + qf.z*kf.z + qf.w*kf.w;
    }
    sc[tk] = d * 0.10206207261596575f;
  }
  float mx = fmaxf(fmaxf(sc[0],sc[1]),fmaxf(sc[2],sc[3]));
  float s = 0.f;
  #pragma unroll
  for (int tk=0;tk<4;++tk){ sc[tk]=__expf(sc[tk]-mx); s+=sc[tk]; }
  float inv = 1.f/s;
  #pragma unroll
  for (int tk=0;tk<4;++tk) sc[tk]*=inv;
  float4* op = (float4*)(O + (row0 + tq)*DMODEL + h*96);
  #pragma unroll 4
  for (int j = 0; j < 24; ++j) {
    float4 o = {0.f,0.f,0.f,0.f};
    #pragma unroll
    for (int tk=0;tk<4;++tk){
      const float4* vp = (const float4*)(QKV + (row0+tk)*1152 + 768 + h*96);
      float4 vf = vp[j];
      o.x += sc[tk]*vf.x; o.y += sc[tk]*vf.y; o.z += sc[tk]*vf.z; o.w += sc[tk]*vf.w;
    }
    op[j] = o;
  }
}

extern "C" void kernel_launch(void* const* d_in, const int* in_sizes, int n_in,
                              void* d_out, int out_size, void* d_ws, size_t ws_size,
                              hipStream_t stream)
{
  (void)in_sizes; (void)n_in; (void)out_size;
  const float* x         = (const float*)d_in[0];
  const float* r_w1      = (const float*)d_in[1];
  const float* r_b1      = (const float*)d_in[2];
  const float* r_w2      = (const float*)d_in[3];
  const float* r_b2      = (const float*)d_in[4];
  const float* ln1_w     = (const float*)d_in[5];
  const float* ln1_b     = (const float*)d_in[6];
  const float* ln2_w     = (const float*)d_in[7];
  const float* ln2_b     = (const float*)d_in[8];
  const float* in_proj_w = (const float*)d_in[9];
  const float* conv_w    = (const float*)d_in[10];
  const float* conv_b    = (const float*)d_in[11];
  const float* x_proj_w  = (const float*)d_in[12];
  const float* dt_proj_w = (const float*)d_in[13];
  const float* dt_proj_b = (const float*)d_in[14];
  const float* A_log     = (const float*)d_in[15];
  const float* D_skip    = (const float*)d_in[16];
  const float* out_proj_w= (const float*)d_in[17];
  const float* qkv_w     = (const float*)d_in[18];
  const float* qkv_b     = (const float*)d_in[19];
  const float* ao_w      = (const float*)d_in[20];
  const float* ao_b      = (const float*)d_in[21];
  const float* gate      = (const float*)d_in[22];
  const float* lng_w     = (const float*)d_in[23];
  const float* lng_b     = (const float*)d_in[24];

  float* ws = (float*)d_ws;
  float* WR = ws;            // 32 floats
  float* G  = ws + 64;       // 3072 floats
  u16*  WBF = (u16*)(ws + 3200);          // 1,609,728 u16 = 804,864 floats
  // weight offsets in WBF (u16 units)
  u16* ipw = WBF + 0;        // 1536*384
  u16* xpw = WBF + 589824;   // 152*768
  u16* dtw = WBF + 706560;   // 768*24
  u16* opw = WBF + 724992;   // 384*768
  u16* qkw = WBF + 1019904;  // 1152*384
  u16* aow = WBF + 1462272;  // 384*384  (end 1609728)

  int BS = 8;
  while (BS > 1) {
    size_t need = ((size_t)808064 + (size_t)BS*1024*3608) * sizeof(float);
    if (need <= ws_size) break;
    BS >>= 1;
  }
  const int R = BS * 1024;

  (void)hipMemsetAsync(ws, 0, 4096*sizeof(float), stream);
  router_mean_kernel<<<dim3(16,8),384,0,stream>>>(x, G);
  router_mlp_kernel<<<8,96,0,stream>>>(G, r_w1, r_b1, r_w2, r_b2, WR);

  // weight conversions (n/4 threads each)
  cvt4_kernel<<<576,256,0,stream>>>(in_proj_w, ipw, 147456);
  cvt4_kernel<<<114,256,0,stream>>>(x_proj_w,  xpw, 29184);
  cvt4_kernel<<<18,256,0,stream>>>(dt_proj_w,  dtw, 4608);
  cvt4_kernel<<<288,256,0,stream>>>(out_proj_w,opw, 73728);
  cvt4_kernel<<<432,256,0,stream>>>(qkv_w,     qkw, 110592);
  cvt4_kernel<<<144,256,0,stream>>>(ao_w,      aow, 36864);

  float* base = ws + 808064;
  u16*   ABF  = (u16*)base;                    // R*768 u16 (R*384 fl)
  float* XZ   = base + (size_t)R*384;          // R*1536
  u16*   Ub   = (u16*)(XZ + (size_t)R*1536);   // R*768 u16 (R*384 fl)
  float* XDBL = XZ + (size_t)R*1920;           // R*152
  u16*   DTb  = (u16*)(XDBL + (size_t)R*152);  // R*768 u16 (R*384 fl)
  float* SACC = XDBL + (size_t)R*536;          // R*768
  // aliases (post-scan lifetimes)
  float* X2   = (float*)Ub;                    // R*384
  float* XN2  = SACC;                          // R*384
  float* AOb  = SACC + (size_t)R*384;          // R*384
  float* QKV  = XZ;                            // R*1152
  float* ATTO = (float*)DTb;                   // R*384

  for (int s = 0; s < 8/BS; ++s) {
    const int b0 = s * BS;
    const size_t xoff = (size_t)b0 * NSEQ * DMODEL;

    ln_bf16out_kernel<<<R/4,256,0,stream>>>(x + xoff, ln1_w, ln1_b, ABF);
    mgemm_kernel<<<dim3(24,R/256),256,0,stream>>>(ABF,384, ipw,384,1536, nullptr,nullptr,0,0, XZ,1536);
    zsilu_kernel<<<(R*192)/256,256,0,stream>>>(XZ);
    for (int dir = 0; dir < 4; ++dir) {
      switch (dir) {
        case 0: conv_silu_kernel<0><<<3*R,256,0,stream>>>(XZ, conv_w, conv_b, Ub); break;
        case 1: conv_silu_kernel<1><<<3*R,256,0,stream>>>(XZ, conv_w, conv_b, Ub); break;
        case 2: conv_silu_kernel<2><<<3*R,256,0,stream>>>(XZ, conv_w, conv_b, Ub); break;
        default: conv_silu_kernel<3><<<3*R,256,0,stream>>>(XZ, conv_w, conv_b, Ub); break;
      }
      mgemm_kernel<<<dim3(3,R/256),256,0,stream>>>(Ub,768, xpw,768,152, nullptr,nullptr,0,0, XDBL,152);
      cvt4_kernel<<<(R*38)/256,256,0,stream>>>(XDBL, ABF, R*38);
      mgemm_kernel<<<dim3(12,R/256),256,0,stream>>>(ABF,152, dtw,24,768, dt_proj_b,nullptr,1,1, DTb,768);
      switch (dir) {
        case 0: scan_kernel<0><<<dim3(48,BS),256,0,stream>>>(XDBL, DTb, Ub, XZ, A_log, D_skip, WR, SACC, b0); break;
        case 1: scan_kernel<1><<<dim3(48,BS),256,0,stream>>>(XDBL, DTb, Ub, XZ, A_log, D_skip, WR, SACC, b0); break;
        case 2: scan_kernel<2><<<dim3(48,BS),256,0,stream>>>(XDBL, DTb, Ub, XZ, A_log, D_skip, WR, SACC, b0); break;
        default: scan_kernel<3><<<dim3(48,BS),256,0,stream>>>(XDBL, DTb, Ub, XZ, A_log, D_skip, WR, SACC, b0); break;
      }
    }
    cvt4_kernel<<<(R*192)/256,256,0,stream>>>(SACC, ABF, R*192);
    mgemm_kernel<<<dim3(6,R/256),256,0,stream>>>(ABF,768, opw,768,384, nullptr,x + xoff,0,0, X2,384);
    ln_kernel<<<R/4,256,0,stream>>>(X2, ln2_w, ln2_b, XN2);
    cvt4_kernel<<<(R*96)/256,256,0,stream>>>(XN2, ABF, R*96);
    mgemm_kernel<<<dim3(18,R/256),256,0,stream>>>(ABF,384, qkw,384,1152, qkv_b,nullptr,0,0, QKV,1152);
    attn_kernel<<<R/64,256,0,stream>>>(QKV, ATTO);
    cvt4_kernel<<<(R*96)/256,256,0,stream>>>(ATTO, ABF, R*96);
    mgemm_kernel<<<dim3(6,R/256),256,0,stream>>>(ABF,384, aow,384,384, ao_b,nullptr,0,0, AOb,384);
    ln_final_kernel<<<R/4,256,0,stream>>>(XN2, AOb, gate, lng_w, lng_b, (float*)d_out + xoff);
  }
}

// Round 10
// 1951.789 us; speedup vs baseline: 1.9503x; 1.0904x over previous
//
#include <hip/hip_runtime.h>
#include <math.h>

// ASMambaBlock: router + 4-dir Mamba (fused concurrent scans) + windowed MHA.
// bf16 MFMA GEMMs; 4 direction-scans in ONE dispatch (atomicAdd accumulate).
// ws floats: WR 0 | G 64 | WBF @3200 | slices @808064.
// Per-slice: ABF R*384 | XZbf R*768 | Ub4 R*1536 | XD4 R*304 | DT4 R*1536
// | SACC R*768 = R*5296 floats. BS=8 -> 176.7 MB, BS=4 -> 89.9 MB (auto).

#define NSEQ  1024
#define DMODEL 384
#define DINNER 768
#define DSTATE 64
#define XW 152

typedef unsigned short u16;
typedef __attribute__((ext_vector_type(8))) short short8;
typedef __attribute__((ext_vector_type(4))) float f32x4;

__device__ __forceinline__ float bf2f(u16 u){
  union { unsigned int i; float f; } c; c.i = ((unsigned int)u) << 16; return c.f;
}
__device__ __forceinline__ u16 f2bf(float f){
  union { float f; unsigned int i; } c; c.f = f;
  unsigned int x = c.i;
  return (u16)((x + 0x7fffu + ((x >> 16) & 1u)) >> 16);
}
__device__ __forceinline__ float4 unp4(uint2 u){
  float4 f;
  f.x = bf2f((u16)(u.x & 0xffffu)); f.y = bf2f((u16)(u.x >> 16));
  f.z = bf2f((u16)(u.y & 0xffffu)); f.w = bf2f((u16)(u.y >> 16));
  return f;
}

template<int DIR>
__device__ __forceinline__ int permi(int i){
  if (DIR == 0) return i;
  if (DIR == 1) return ((i & 31) << 5) | (i >> 5);
  if (DIR == 2) return 1023 - i;
  int j = 1023 - i; return ((j & 31) << 5) | (j >> 5);
}

// ---------------- router ----------------
__global__ __launch_bounds__(384) void router_mean_kernel(const float* __restrict__ X, float* __restrict__ G){
  int b = blockIdx.y, chunk = blockIdx.x, c = threadIdx.x;
  float s = 0.f;
  const float* xp = X + ((size_t)b*NSEQ + (size_t)chunk*64)*DMODEL + c;
  for (int l = 0; l < 64; ++l) s += xp[(size_t)l*DMODEL];
  atomicAdd(&G[b*DMODEL + c], s * (1.f/1024.f));
}

__global__ __launch_bounds__(96) void router_mlp_kernel(const float* __restrict__ G,
    const float* __restrict__ w1, const float* __restrict__ b1,
    const float* __restrict__ w2, const float* __restrict__ b2, float* __restrict__ WR){
  int b = blockIdx.x, j = threadIdx.x;
  __shared__ float hs[96];
  __shared__ float ls[4];
  float a = b1[j];
  const float* g = G + b*DMODEL;
  for (int c = 0; c < DMODEL; ++c) a += g[c] * w1[j*DMODEL + c];
  hs[j] = 0.5f * a * (1.f + erff(a * 0.70710678118654752f));
  __syncthreads();
  if (j < 4) {
    float lg = b2[j];
    for (int jj = 0; jj < 96; ++jj) lg += hs[jj] * w2[j*96 + jj];
    ls[j] = lg;
  }
  __syncthreads();
  if (j == 0) {
    float mx = fmaxf(fmaxf(ls[0],ls[1]),fmaxf(ls[2],ls[3]));
    float e0=__expf(ls[0]-mx), e1=__expf(ls[1]-mx), e2=__expf(ls[2]-mx), e3=__expf(ls[3]-mx);
    float s = e0+e1+e2+e3;
    WR[b*4+0]=e0/s; WR[b*4+1]=e1/s; WR[b*4+2]=e2/s; WR[b*4+3]=e3/s;
  }
}

// ---------------- layernorms ----------------
__global__ __launch_bounds__(256) void ln_bf16out_kernel(const float* __restrict__ X,
    const float* __restrict__ w, const float* __restrict__ bb, u16* __restrict__ O){
  int row = blockIdx.x*4 + (threadIdx.x >> 6);
  int lane = threadIdx.x & 63;
  const float* xr = X + (size_t)row*DMODEL;
  float v[6]; float s=0.f, s2=0.f;
  #pragma unroll
  for (int j=0;j<6;++j){ float t = xr[lane + j*64]; v[j]=t; s+=t; s2+=t*t; }
  #pragma unroll
  for (int m=1;m<64;m<<=1){ s += __shfl_xor(s,m,64); s2 += __shfl_xor(s2,m,64); }
  float mu = s*(1.f/DMODEL);
  float rs = rsqrtf(s2*(1.f/DMODEL) - mu*mu + 1e-5f);
  u16* o = O + (size_t)row*DMODEL;
  #pragma unroll
  for (int j=0;j<6;++j){ int i = lane+j*64; o[i] = f2bf((v[j]-mu)*rs*w[i] + bb[i]); }
}

__global__ __launch_bounds__(256) void ln_kernel(const float* __restrict__ X,
    const float* __restrict__ w, const float* __restrict__ bb, float* __restrict__ O){
  int row = blockIdx.x*4 + (threadIdx.x >> 6);
  int lane = threadIdx.x & 63;
  const float* xr = X + (size_t)row*DMODEL;
  float v[6]; float s=0.f, s2=0.f;
  #pragma unroll
  for (int j=0;j<6;++j){ float t = xr[lane + j*64]; v[j]=t; s+=t; s2+=t*t; }
  #pragma unroll
  for (int m=1;m<64;m<<=1){ s += __shfl_xor(s,m,64); s2 += __shfl_xor(s2,m,64); }
  float mu = s*(1.f/DMODEL);
  float rs = rsqrtf(s2*(1.f/DMODEL) - mu*mu + 1e-5f);
  float* o = O + (size_t)row*DMODEL;
  #pragma unroll
  for (int j=0;j<6;++j){ int i = lane+j*64; o[i] = (v[j]-mu)*rs*w[i] + bb[i]; }
}

__global__ __launch_bounds__(256) void ln_final_kernel(const float* __restrict__ XN2,
    const float* __restrict__ AO, const float* __restrict__ gatep,
    const float* __restrict__ w, const float* __restrict__ bb, float* __restrict__ OUT){
  int row = blockIdx.x*4 + (threadIdx.x >> 6);
  int lane = threadIdx.x & 63;
  float gate = gatep[0];
  const float* xr = XN2 + (size_t)row*DMODEL;
  const float* ar = AO + (size_t)row*DMODEL;
  float v[6]; float s=0.f, s2=0.f;
  #pragma unroll
  for (int j=0;j<6;++j){ int i = lane+j*64; float t = xr[i] + gate*ar[i]; v[j]=t; s+=t; s2+=t*t; }
  #pragma unroll
  for (int m=1;m<64;m<<=1){ s += __shfl_xor(s,m,64); s2 += __shfl_xor(s2,m,64); }
  float mu = s*(1.f/DMODEL);
  float rs = rsqrtf(s2*(1.f/DMODEL) - mu*mu + 1e-5f);
  float* o = OUT + (size_t)row*DMODEL;
  #pragma unroll
  for (int j=0;j<6;++j){ int i = lane+j*64; o[i] = (v[j]-mu)*rs*w[i] + bb[i]; }
}

// ---------------- f32 -> bf16 conversion ----------------
__global__ __launch_bounds__(256) void cvt4_kernel(const float* __restrict__ src,
    u16* __restrict__ dst, int n4){
  int i = blockIdx.x*256 + threadIdx.x;
  if (i >= n4) return;
  float4 v = ((const float4*)src)[i];
  ushort4 o; o.x=f2bf(v.x); o.y=f2bf(v.y); o.z=f2bf(v.z); o.w=f2bf(v.w);
  ((ushort4*)dst)[i] = o;
}

// ---------------- bf16 MFMA GEMM ----------------
__global__ __launch_bounds__(256) void mgemm_kernel(
    const u16* __restrict__ A, int lda,
    const u16* __restrict__ W, int K, int N,
    const float* __restrict__ bias,
    const float* __restrict__ resid,
    int act,                 // 0 none, 1 softplus
    int obf,                 // 0: f32 out, 1: bf16 out
    void* __restrict__ C, int ldc)
{
  const int lane = threadIdx.x & 63;
  const int wv = threadIdx.x >> 6;
  const int m0 = (blockIdx.y*4 + wv) * 64;
  const int n0 = blockIdx.x * 64;
  const int r  = lane & 15;
  const int kg = lane >> 4;
  f32x4 acc[4][4];
  #pragma unroll
  for (int i=0;i<4;++i){
    #pragma unroll
    for (int j=0;j<4;++j) acc[i][j] = (f32x4)0.f;
  }
  for (int k0 = 0; k0 < K; k0 += 32) {
    const bool kval = (k0 + kg*8) < K;
    short8 a[4], b[4];
    #pragma unroll
    for (int i = 0; i < 4; ++i) {
      a[i] = kval ? *(const short8*)(A + (size_t)(m0 + i*16 + r)*lda + k0 + kg*8) : (short8)0;
      int n = n0 + i*16 + r;
      b[i] = (kval && n < N) ? *(const short8*)(W + (size_t)n*K + k0 + kg*8) : (short8)0;
    }
    #pragma unroll
    for (int ai = 0; ai < 4; ++ai)
      #pragma unroll
      for (int bi = 0; bi < 4; ++bi)
        acc[ai][bi] = __builtin_amdgcn_mfma_f32_16x16x32_bf16(a[ai], b[bi], acc[ai][bi], 0, 0, 0);
  }
  #pragma unroll
  for (int ai = 0; ai < 4; ++ai) {
    int mrow = m0 + ai*16 + kg*4;
    #pragma unroll
    for (int bi = 0; bi < 4; ++bi) {
      int n = n0 + bi*16 + r;
      if (n < N) {
        #pragma unroll
        for (int q = 0; q < 4; ++q) {
          float v = acc[ai][bi][q];
          int m = mrow + q;
          if (bias) v += bias[n];
          if (act == 1) v = (v > 20.f) ? v : log1pf(__expf(v));
          if (resid) v += resid[(size_t)m*ldc + n];
          if (obf) ((u16*)C)[(size_t)m*ldc + n] = f2bf(v);
          else     ((float*)C)[(size_t)m*ldc + n] = v;
        }
      }
    }
  }
}

// ---------------- in-place silu on z-half of XZbf ----------------
__global__ __launch_bounds__(256) void zsilu_kernel(u16* __restrict__ XZ){
  int idx = blockIdx.x*256 + threadIdx.x;       // R*96 threads, 8 bf16 each
  int row = idx / 96, q = idx % 96;
  u16* p = XZ + (size_t)row*1536 + DINNER + q*8;
  uint4 v = *(uint4*)p;
  unsigned w0=v.x, w1=v.y, w2=v.z, w3=v.w;
  #define ZS(w) { \
    float lo = bf2f((u16)((w) & 0xffffu)); \
    float hi = bf2f((u16)((w) >> 16)); \
    lo = lo / (1.f + __expf(-lo)); \
    hi = hi / (1.f + __expf(-hi)); \
    (w) = (unsigned)f2bf(lo) | ((unsigned)f2bf(hi) << 16); }
  ZS(w0) ZS(w1) ZS(w2) ZS(w3)
  #undef ZS
  v.x=w0; v.y=w1; v.z=w2; v.w=w3;
  *(uint4*)p = v;
}

// ---------------- depthwise causal conv (k=4) + silu, bf16 in/out ----------------
template<int DIR>
__global__ __launch_bounds__(256) void conv_silu_kernel(const u16* __restrict__ XZ,
    const float* __restrict__ cw, const float* __restrict__ cb, u16* __restrict__ Uo){
  int idx = blockIdx.x*256 + threadIdx.x;        // b*1024*768 + i*768 + c
  int c = idx % DINNER;
  int rest = idx / DINNER;
  int i = rest & 1023;
  int b = rest >> 10;
  float acc = cb[c];
  #pragma unroll
  for (int k = 0; k < 4; ++k) {
    int ii = i - 3 + k;
    if (ii >= 0)
      acc += cw[c*4 + k] * bf2f(XZ[((size_t)b*NSEQ + permi<DIR>(ii))*1536 + c]);
  }
  Uo[idx] = f2bf(acc / (1.f + __expf(-acc)));
}

// ---------------- fused 4-direction selective scan ----------------
template<int CTRL>
__device__ __forceinline__ float dpp_add(float v){
  int t = __builtin_amdgcn_update_dpp(0, __float_as_int(v), CTRL, 0xf, 0xf, true);
  return v + __int_as_float(t);
}
__device__ __forceinline__ float wave64_reduce_hi(float p){
  p = dpp_add<0x128>(p);
  p = dpp_add<0x124>(p);
  p = dpp_add<0x122>(p);
  p = dpp_add<0x121>(p);
  p = dpp_add<0x142>(p);
  p = dpp_add<0x143>(p);
  return p;              // lanes 48..63 = total
}

// Per-wave structure identical to round-9 proven shape (4 ch/wave, 16 ch/block);
// dir = blockIdx.z -> 4x waves in flight; accumulate via atomicAdd (SACC zeroed).
template<int DIR>
__device__ __forceinline__ void scan_body(
    const u16* __restrict__ xd,   // per-(dir,b) XD rows [1024][152] bf16
    const u16* __restrict__ dt0,  // per-(dir,b) DT rows [1024][768] bf16
    const u16* __restrict__ u0,
    const u16* __restrict__ z0,   // XZbf + b*1024*1536 (u16)
    float* __restrict__ sp0,      // SACC + b*1024*768
    const float* __restrict__ A_log, const float* __restrict__ Dskip, float wgt)
{
  const int lane = threadIdx.x & 63;
  const int wave = threadIdx.x >> 6;
  const int c0 = blockIdx.x*16 + wave*4;
  const float L2E = 1.4426950408889634f;
  const float As0 = -__expf(A_log[(c0+0)*DSTATE + lane]) * L2E;
  const float As1 = -__expf(A_log[(c0+1)*DSTATE + lane]) * L2E;
  const float As2 = -__expf(A_log[(c0+2)*DSTATE + lane]) * L2E;
  const float As3 = -__expf(A_log[(c0+3)*DSTATE + lane]) * L2E;
  const float4 dsk = *(const float4*)(Dskip + c0);
  const u16* dtp = dt0 + c0;
  const u16* up  = u0 + c0;
  const u16* zp  = z0 + DINNER + c0;
  float* sp = sp0 + c0;

#define SLOAD(k, l) { int lr = (l) < 1023 ? (l) : 1023;                     \
    const u16* x2 = xd + (size_t)lr*XW;                                     \
    B##k = bf2f(x2[24+lane]); C##k = bf2f(x2[88+lane]);                     \
    uint2 td = *(const uint2*)(dtp + (size_t)lr*DINNER);                    \
    uint2 ud = *(const uint2*)(up  + (size_t)lr*DINNER);                    \
    t##k = unp4(td); v##k = unp4(ud);                                       \
    uint2 zd = *(const uint2*)(zp + (size_t)permi<DIR>(lr)*1536);           \
    w##k = unp4(zd); }

#define SSTEP(k, l) {                                                       \
    float e;                                                                \
    e = exp2f(t##k.x*As0); g0 = e*g0 + (t##k.x*v##k.x)*B##k;                \
    e = exp2f(t##k.y*As1); g1 = e*g1 + (t##k.y*v##k.y)*B##k;                \
    e = exp2f(t##k.z*As2); g2 = e*g2 + (t##k.z*v##k.z)*B##k;                \
    e = exp2f(t##k.w*As3); g3 = e*g3 + (t##k.w*v##k.w)*B##k;                \
    float p0 = wave64_reduce_hi(g0*C##k);                                   \
    float p1 = wave64_reduce_hi(g1*C##k);                                   \
    float p2 = wave64_reduce_hi(g2*C##k);                                   \
    float p3 = wave64_reduce_hi(g3*C##k);                                   \
    if (lane == 63) {                                                       \
      float* o = sp + (size_t)(l)*DINNER;                                   \
      atomicAdd(o+0, wgt*(p0 + v##k.x*dsk.x)*w##k.x);                       \
      atomicAdd(o+1, wgt*(p1 + v##k.y*dsk.y)*w##k.y);                       \
      atomicAdd(o+2, wgt*(p2 + v##k.z*dsk.z)*w##k.z);                       \
      atomicAdd(o+3, wgt*(p3 + v##k.w*dsk.w)*w##k.w); } }

  float B0,C0,B1,C1,B2,C2,B3,C3;
  float4 t0,t1,t2,t3, v0,v1,v2,v3, w0,w1,w2,w3;
  float g0=0.f, g1=0.f, g2=0.f, g3=0.f;
  SLOAD(0,0) SLOAD(1,1) SLOAD(2,2) SLOAD(3,3)
  __builtin_amdgcn_sched_barrier(0);
  for (int l = 0; l < NSEQ; l += 4) {
    SSTEP(0,l)   SLOAD(0,l+4) __builtin_amdgcn_sched_barrier(0);
    SSTEP(1,l+1) SLOAD(1,l+5) __builtin_amdgcn_sched_barrier(0);
    SSTEP(2,l+2) SLOAD(2,l+6) __builtin_amdgcn_sched_barrier(0);
    SSTEP(3,l+3) SLOAD(3,l+7) __builtin_amdgcn_sched_barrier(0);
  }
#undef SLOAD
#undef SSTEP
}

__global__ __launch_bounds__(256) void scan_all_kernel(
    const u16* __restrict__ XD4, const u16* __restrict__ DT4,
    const u16* __restrict__ U4, const u16* __restrict__ XZ,
    const float* __restrict__ A_log, const float* __restrict__ Dskip,
    const float* __restrict__ WR, float* __restrict__ SACC, int b0, int BS)
{
  const int dir = blockIdx.z;
  const int b = blockIdx.y;
  const size_t drb = ((size_t)dir*BS + b) * NSEQ;    // per-dir row base
  const u16* xd = XD4 + drb*XW;
  const u16* dt = DT4 + drb*DINNER;
  const u16* uu = U4  + drb*DINNER;
  const u16* zz = XZ  + (size_t)b*NSEQ*1536;
  float* sp = SACC + (size_t)b*NSEQ*DINNER;
  const float wgt = WR[(b0+b)*4 + dir];
  switch (dir) {
    case 0: scan_body<0>(xd, dt, uu, zz, sp, A_log, Dskip, wgt); break;
    case 1: scan_body<1>(xd, dt, uu, zz, sp, A_log, Dskip, wgt); break;
    case 2: scan_body<2>(xd, dt, uu, zz, sp, A_log, Dskip, wgt); break;
    default: scan_body<3>(xd, dt, uu, zz, sp, A_log, Dskip, wgt); break;
  }
}

// ---------------- windowed attention ----------------
__global__ __launch_bounds__(256) void attn_kernel(const float* __restrict__ QKV, float* __restrict__ O){
  int idx = blockIdx.x*256 + threadIdx.x;
  int tq = idx & 3, h = (idx >> 2) & 3, w = idx >> 4;
  size_t row0 = (size_t)w * 4;
  const float4* qp = (const float4*)(QKV + (row0 + tq)*1152 + h*96);
  float sc[4];
  #pragma unroll
  for (int tk = 0; tk < 4; ++tk) {
    const float4* kp = (const float4*)(QKV + (row0 + tk)*1152 + 384 + h*96);
    float d = 0.f;
    #pragma unroll
    for (int j = 0; j < 24; ++j) {
      float4 qf = qp[j], kf = kp[j];
      d += qf.x*kf.x + qf.y*kf.y + qf.z*kf.z + qf.w*kf.w;
    }
    sc[tk] = d * 0.10206207261596575f;
  }
  float mx = fmaxf(fmaxf(sc[0],sc[1]),fmaxf(sc[2],sc[3]));
  float s = 0.f;
  #pragma unroll
  for (int tk=0;tk<4;++tk){ sc[tk]=__expf(sc[tk]-mx); s+=sc[tk]; }
  float inv = 1.f/s;
  #pragma unroll
  for (int tk=0;tk<4;++tk) sc[tk]*=inv;
  float4* op = (float4*)(O + (row0 + tq)*DMODEL + h*96);
  #pragma unroll 4
  for (int j = 0; j < 24; ++j) {
    float4 o = {0.f,0.f,0.f,0.f};
    #pragma unroll
    for (int tk=0;tk<4;++tk){
      const float4* vp = (const float4*)(QKV + (row0+tk)*1152 + 768 + h*96);
      float4 vf = vp[j];
      o.x += sc[tk]*vf.x; o.y += sc[tk]*vf.y; o.z += sc[tk]*vf.z; o.w += sc[tk]*vf.w;
    }
    op[j] = o;
  }
}

extern "C" void kernel_launch(void* const* d_in, const int* in_sizes, int n_in,
                              void* d_out, int out_size, void* d_ws, size_t ws_size,
                              hipStream_t stream)
{
  (void)in_sizes; (void)n_in; (void)out_size;
  const float* x         = (const float*)d_in[0];
  const float* r_w1      = (const float*)d_in[1];
  const float* r_b1      = (const float*)d_in[2];
  const float* r_w2      = (const float*)d_in[3];
  const float* r_b2      = (const float*)d_in[4];
  const float* ln1_w     = (const float*)d_in[5];
  const float* ln1_b     = (const float*)d_in[6];
  const float* ln2_w     = (const float*)d_in[7];
  const float* ln2_b     = (const float*)d_in[8];
  const float* in_proj_w = (const float*)d_in[9];
  const float* conv_w    = (const float*)d_in[10];
  const float* conv_b    = (const float*)d_in[11];
  const float* x_proj_w  = (const float*)d_in[12];
  const float* dt_proj_w = (const float*)d_in[13];
  const float* dt_proj_b = (const float*)d_in[14];
  const float* A_log     = (const float*)d_in[15];
  const float* D_skip    = (const float*)d_in[16];
  const float* out_proj_w= (const float*)d_in[17];
  const float* qkv_w     = (const float*)d_in[18];
  const float* qkv_b     = (const float*)d_in[19];
  const float* ao_w      = (const float*)d_in[20];
  const float* ao_b      = (const float*)d_in[21];
  const float* gate      = (const float*)d_in[22];
  const float* lng_w     = (const float*)d_in[23];
  const float* lng_b     = (const float*)d_in[24];

  float* ws = (float*)d_ws;
  float* WR = ws;            // 32 floats
  float* G  = ws + 64;       // 3072 floats
  u16*  WBF = (u16*)(ws + 3200);
  u16* ipw = WBF + 0;        // 1536*384
  u16* xpw = WBF + 589824;   // 152*768
  u16* dtw = WBF + 706560;   // 768*24
  u16* opw = WBF + 724992;   // 384*768
  u16* qkw = WBF + 1019904;  // 1152*384
  u16* aow = WBF + 1462272;  // 384*384 (end 1609728 u16 = 804864 fl)

  int BS = 8;
  while (BS > 1) {
    size_t need = ((size_t)808064 + (size_t)BS*1024*5296) * sizeof(float);
    if (need <= ws_size) break;
    BS >>= 1;
  }
  const int R = BS * 1024;

  (void)hipMemsetAsync(ws, 0, 4096*sizeof(float), stream);
  router_mean_kernel<<<dim3(16,8),384,0,stream>>>(x, G);
  router_mlp_kernel<<<8,96,0,stream>>>(G, r_w1, r_b1, r_w2, r_b2, WR);

  cvt4_kernel<<<576,256,0,stream>>>(in_proj_w, ipw, 147456);
  cvt4_kernel<<<114,256,0,stream>>>(x_proj_w,  xpw, 29184);
  cvt4_kernel<<<18,256,0,stream>>>(dt_proj_w,  dtw, 4608);
  cvt4_kernel<<<288,256,0,stream>>>(out_proj_w,opw, 73728);
  cvt4_kernel<<<432,256,0,stream>>>(qkv_w,     qkw, 110592);
  cvt4_kernel<<<144,256,0,stream>>>(ao_w,      aow, 36864);

  float* base = ws + 808064;
  u16*   ABF  = (u16*)base;                        // R*768 u16
  u16*   XZbf = (u16*)(base + (size_t)R*384);      // R*1536 u16
  u16*   Ub4  = (u16*)(base + (size_t)R*1152);     // 4R*768 u16
  u16*   XD4  = (u16*)(base + (size_t)R*2688);     // 4R*152 u16
  u16*   DT4  = (u16*)(base + (size_t)R*2992);     // 4R*768 u16
  float* SACC = base + (size_t)R*4528;             // R*768 f32 (end R*5296)
  // post-scan aliases
  float* X2   = (float*)Ub4;                       // R*384
  float* QKV  = (float*)Ub4 + (size_t)R*384;       // R*1152
  float* XN2  = SACC;                              // R*384
  float* AOb  = SACC + (size_t)R*384;              // R*384
  float* ATTO = (float*)DT4;                       // R*384

  for (int s = 0; s < 8/BS; ++s) {
    const int b0 = s * BS;
    const size_t xoff = (size_t)b0 * NSEQ * DMODEL;

    (void)hipMemsetAsync(SACC, 0, (size_t)R*768*sizeof(float), stream);
    ln_bf16out_kernel<<<R/4,256,0,stream>>>(x + xoff, ln1_w, ln1_b, ABF);
    mgemm_kernel<<<dim3(24,R/256),256,0,stream>>>(ABF,384, ipw,384,1536, nullptr,nullptr,0,1, XZbf,1536);
    zsilu_kernel<<<(R*96)/256,256,0,stream>>>(XZbf);
    conv_silu_kernel<0><<<3*R,256,0,stream>>>(XZbf, conv_w, conv_b, Ub4);
    conv_silu_kernel<1><<<3*R,256,0,stream>>>(XZbf, conv_w, conv_b, Ub4 + (size_t)R*768);
    conv_silu_kernel<2><<<3*R,256,0,stream>>>(XZbf, conv_w, conv_b, Ub4 + (size_t)2*R*768);
    conv_silu_kernel<3><<<3*R,256,0,stream>>>(XZbf, conv_w, conv_b, Ub4 + (size_t)3*R*768);
    // batched over dirs: M = 4R
    mgemm_kernel<<<dim3(3,R/64),256,0,stream>>>(Ub4,768, xpw,768,152, nullptr,nullptr,0,1, XD4,152);
    mgemm_kernel<<<dim3(12,R/64),256,0,stream>>>(XD4,152, dtw,24,768, dt_proj_b,nullptr,1,1, DT4,768);
    scan_all_kernel<<<dim3(48,BS,4),256,0,stream>>>(XD4, DT4, Ub4, XZbf, A_log, D_skip, WR, SACC, b0, BS);
    cvt4_kernel<<<(R*192)/256,256,0,stream>>>(SACC, ABF, R*192);
    mgemm_kernel<<<dim3(6,R/256),256,0,stream>>>(ABF,768, opw,768,384, nullptr,x + xoff,0,0, X2,384);
    ln_kernel<<<R/4,256,0,stream>>>(X2, ln2_w, ln2_b, XN2);
    cvt4_kernel<<<(R*96)/256,256,0,stream>>>(XN2, ABF, R*96);
    mgemm_kernel<<<dim3(18,R/256),256,0,stream>>>(ABF,384, qkw,384,1152, qkv_b,nullptr,0,0, QKV,1152);
    attn_kernel<<<R/64,256,0,stream>>>(QKV, ATTO);
    cvt4_kernel<<<(R*96)/256,256,0,stream>>>(ATTO, ABF, R*96);
    mgemm_kernel<<<dim3(6,R/256),256,0,stream>>>(ABF,384, aow,384,384, ao_b,nullptr,0,0, AOb,384);
    ln_final_kernel<<<R/4,256,0,stream>>>(XN2, AOb, gate, lng_w, lng_b, (float*)d_out + xoff);
  }
}

// Round 11
// 1949.140 us; speedup vs baseline: 1.9530x; 1.0014x over previous
//
#include <hip/hip_runtime.h>
#include <math.h>

// ASMambaBlock: router + 4-dir Mamba (fused concurrent scans) + windowed MHA.
// bf16 MFMA GEMMs; 4 direction-scans in ONE dispatch (atomicAdd accumulate).
// ws floats: WR 0 | G 64 | WBF @3200 | slices @808064.
// Per-slice: ABF R*384 | XZbf R*768 | Ub4 R*1536 | XD4 R*304 | DT4 R*1536
// | SACC R*768 = R*5296 floats. BS=8 -> 176.7 MB, BS=4 -> 89.9 MB (auto).

#define NSEQ  1024
#define DMODEL 384
#define DINNER 768
#define DSTATE 64
#define XW 152

typedef unsigned short u16;
typedef __attribute__((ext_vector_type(8))) short short8;
typedef __attribute__((ext_vector_type(4))) float f32x4;

__device__ __forceinline__ float bf2f(u16 u){
  union { unsigned int i; float f; } c; c.i = ((unsigned int)u) << 16; return c.f;
}
__device__ __forceinline__ u16 f2bf(float f){
  union { float f; unsigned int i; } c; c.f = f;
  unsigned int x = c.i;
  return (u16)((x + 0x7fffu + ((x >> 16) & 1u)) >> 16);
}
__device__ __forceinline__ float4 unp4(uint2 u){
  float4 f;
  f.x = bf2f((u16)(u.x & 0xffffu)); f.y = bf2f((u16)(u.x >> 16));
  f.z = bf2f((u16)(u.y & 0xffffu)); f.w = bf2f((u16)(u.y >> 16));
  return f;
}

template<int DIR>
__device__ __forceinline__ int permi(int i){
  if (DIR == 0) return i;
  if (DIR == 1) return ((i & 31) << 5) | (i >> 5);
  if (DIR == 2) return 1023 - i;
  int j = 1023 - i; return ((j & 31) << 5) | (j >> 5);
}

// ---------------- router ----------------
__global__ __launch_bounds__(384) void router_mean_kernel(const float* __restrict__ X, float* __restrict__ G){
  int b = blockIdx.y, chunk = blockIdx.x, c = threadIdx.x;
  float s = 0.f;
  const float* xp = X + ((size_t)b*NSEQ + (size_t)chunk*64)*DMODEL + c;
  for (int l = 0; l < 64; ++l) s += xp[(size_t)l*DMODEL];
  atomicAdd(&G[b*DMODEL + c], s * (1.f/1024.f));
}

__global__ __launch_bounds__(96) void router_mlp_kernel(const float* __restrict__ G,
    const float* __restrict__ w1, const float* __restrict__ b1,
    const float* __restrict__ w2, const float* __restrict__ b2, float* __restrict__ WR){
  int b = blockIdx.x, j = threadIdx.x;
  __shared__ float hs[96];
  __shared__ float ls[4];
  float a = b1[j];
  const float* g = G + b*DMODEL;
  for (int c = 0; c < DMODEL; ++c) a += g[c] * w1[j*DMODEL + c];
  hs[j] = 0.5f * a * (1.f + erff(a * 0.70710678118654752f));
  __syncthreads();
  if (j < 4) {
    float lg = b2[j];
    for (int jj = 0; jj < 96; ++jj) lg += hs[jj] * w2[j*96 + jj];
    ls[j] = lg;
  }
  __syncthreads();
  if (j == 0) {
    float mx = fmaxf(fmaxf(ls[0],ls[1]),fmaxf(ls[2],ls[3]));
    float e0=__expf(ls[0]-mx), e1=__expf(ls[1]-mx), e2=__expf(ls[2]-mx), e3=__expf(ls[3]-mx);
    float s = e0+e1+e2+e3;
    WR[b*4+0]=e0/s; WR[b*4+1]=e1/s; WR[b*4+2]=e2/s; WR[b*4+3]=e3/s;
  }
}

// ---------------- layernorms ----------------
__global__ __launch_bounds__(256) void ln_bf16out_kernel(const float* __restrict__ X,
    const float* __restrict__ w, const float* __restrict__ bb, u16* __restrict__ O){
  int row = blockIdx.x*4 + (threadIdx.x >> 6);
  int lane = threadIdx.x & 63;
  const float* xr = X + (size_t)row*DMODEL;
  float v[6]; float s=0.f, s2=0.f;
  #pragma unroll
  for (int j=0;j<6;++j){ float t = xr[lane + j*64]; v[j]=t; s+=t; s2+=t*t; }
  #pragma unroll
  for (int m=1;m<64;m<<=1){ s += __shfl_xor(s,m,64); s2 += __shfl_xor(s2,m,64); }
  float mu = s*(1.f/DMODEL);
  float rs = rsqrtf(s2*(1.f/DMODEL) - mu*mu + 1e-5f);
  u16* o = O + (size_t)row*DMODEL;
  #pragma unroll
  for (int j=0;j<6;++j){ int i = lane+j*64; o[i] = f2bf((v[j]-mu)*rs*w[i] + bb[i]); }
}

__global__ __launch_bounds__(256) void ln_kernel(const float* __restrict__ X,
    const float* __restrict__ w, const float* __restrict__ bb, float* __restrict__ O){
  int row = blockIdx.x*4 + (threadIdx.x >> 6);
  int lane = threadIdx.x & 63;
  const float* xr = X + (size_t)row*DMODEL;
  float v[6]; float s=0.f, s2=0.f;
  #pragma unroll
  for (int j=0;j<6;++j){ float t = xr[lane + j*64]; v[j]=t; s+=t; s2+=t*t; }
  #pragma unroll
  for (int m=1;m<64;m<<=1){ s += __shfl_xor(s,m,64); s2 += __shfl_xor(s2,m,64); }
  float mu = s*(1.f/DMODEL);
  float rs = rsqrtf(s2*(1.f/DMODEL) - mu*mu + 1e-5f);
  float* o = O + (size_t)row*DMODEL;
  #pragma unroll
  for (int j=0;j<6;++j){ int i = lane+j*64; o[i] = (v[j]-mu)*rs*w[i] + bb[i]; }
}

__global__ __launch_bounds__(256) void ln_final_kernel(const float* __restrict__ XN2,
    const float* __restrict__ AO, const float* __restrict__ gatep,
    const float* __restrict__ w, const float* __restrict__ bb, float* __restrict__ OUT){
  int row = blockIdx.x*4 + (threadIdx.x >> 6);
  int lane = threadIdx.x & 63;
  float gate = gatep[0];
  const float* xr = XN2 + (size_t)row*DMODEL;
  const float* ar = AO + (size_t)row*DMODEL;
  float v[6]; float s=0.f, s2=0.f;
  #pragma unroll
  for (int j=0;j<6;++j){ int i = lane+j*64; float t = xr[i] + gate*ar[i]; v[j]=t; s+=t; s2+=t*t; }
  #pragma unroll
  for (int m=1;m<64;m<<=1){ s += __shfl_xor(s,m,64); s2 += __shfl_xor(s2,m,64); }
  float mu = s*(1.f/DMODEL);
  float rs = rsqrtf(s2*(1.f/DMODEL) - mu*mu + 1e-5f);
  float* o = OUT + (size_t)row*DMODEL;
  #pragma unroll
  for (int j=0;j<6;++j){ int i = lane+j*64; o[i] = (v[j]-mu)*rs*w[i] + bb[i]; }
}

// ---------------- f32 -> bf16 conversion ----------------
__global__ __launch_bounds__(256) void cvt4_kernel(const float* __restrict__ src,
    u16* __restrict__ dst, int n4){
  int i = blockIdx.x*256 + threadIdx.x;
  if (i >= n4) return;
  float4 v = ((const float4*)src)[i];
  ushort4 o; o.x=f2bf(v.x); o.y=f2bf(v.y); o.z=f2bf(v.z); o.w=f2bf(v.w);
  ((ushort4*)dst)[i] = o;
}

// ---------------- bf16 MFMA GEMM ----------------
__global__ __launch_bounds__(256) void mgemm_kernel(
    const u16* __restrict__ A, int lda,
    const u16* __restrict__ W, int K, int N,
    const float* __restrict__ bias,
    const float* __restrict__ resid,
    int act,                 // 0 none, 1 softplus
    int obf,                 // 0: f32 out, 1: bf16 out
    void* __restrict__ C, int ldc)
{
  const int lane = threadIdx.x & 63;
  const int wv = threadIdx.x >> 6;
  const int m0 = (blockIdx.y*4 + wv) * 64;
  const int n0 = blockIdx.x * 64;
  const int r  = lane & 15;
  const int kg = lane >> 4;
  f32x4 acc[4][4];
  #pragma unroll
  for (int i=0;i<4;++i){
    #pragma unroll
    for (int j=0;j<4;++j) acc[i][j] = (f32x4)0.f;
  }
  for (int k0 = 0; k0 < K; k0 += 32) {
    const bool kval = (k0 + kg*8) < K;
    short8 a[4], b[4];
    #pragma unroll
    for (int i = 0; i < 4; ++i) {
      a[i] = kval ? *(const short8*)(A + (size_t)(m0 + i*16 + r)*lda + k0 + kg*8) : (short8)0;
      int n = n0 + i*16 + r;
      b[i] = (kval && n < N) ? *(const short8*)(W + (size_t)n*K + k0 + kg*8) : (short8)0;
    }
    #pragma unroll
    for (int ai = 0; ai < 4; ++ai)
      #pragma unroll
      for (int bi = 0; bi < 4; ++bi)
        acc[ai][bi] = __builtin_amdgcn_mfma_f32_16x16x32_bf16(a[ai], b[bi], acc[ai][bi], 0, 0, 0);
  }
  #pragma unroll
  for (int ai = 0; ai < 4; ++ai) {
    int mrow = m0 + ai*16 + kg*4;
    #pragma unroll
    for (int bi = 0; bi < 4; ++bi) {
      int n = n0 + bi*16 + r;
      if (n < N) {
        #pragma unroll
        for (int q = 0; q < 4; ++q) {
          float v = acc[ai][bi][q];
          int m = mrow + q;
          if (bias) v += bias[n];
          if (act == 1) v = (v > 20.f) ? v : log1pf(__expf(v));
          if (resid) v += resid[(size_t)m*ldc + n];
          if (obf) ((u16*)C)[(size_t)m*ldc + n] = f2bf(v);
          else     ((float*)C)[(size_t)m*ldc + n] = v;
        }
      }
    }
  }
}

// ---------------- in-place silu on z-half of XZbf ----------------
__global__ __launch_bounds__(256) void zsilu_kernel(u16* __restrict__ XZ){
  int idx = blockIdx.x*256 + threadIdx.x;       // R*96 threads, 8 bf16 each
  int row = idx / 96, q = idx % 96;
  u16* p = XZ + (size_t)row*1536 + DINNER + q*8;
  uint4 v = *(uint4*)p;
  unsigned w0=v.x, w1=v.y, w2=v.z, w3=v.w;
  #define ZS(w) { \
    float lo = bf2f((u16)((w) & 0xffffu)); \
    float hi = bf2f((u16)((w) >> 16)); \
    lo = lo / (1.f + __expf(-lo)); \
    hi = hi / (1.f + __expf(-hi)); \
    (w) = (unsigned)f2bf(lo) | ((unsigned)f2bf(hi) << 16); }
  ZS(w0) ZS(w1) ZS(w2) ZS(w3)
  #undef ZS
  v.x=w0; v.y=w1; v.z=w2; v.w=w3;
  *(uint4*)p = v;
}

// ---------------- depthwise causal conv (k=4) + silu, bf16 in/out ----------------
template<int DIR>
__global__ __launch_bounds__(256) void conv_silu_kernel(const u16* __restrict__ XZ,
    const float* __restrict__ cw, const float* __restrict__ cb, u16* __restrict__ Uo){
  int idx = blockIdx.x*256 + threadIdx.x;        // b*1024*768 + i*768 + c
  int c = idx % DINNER;
  int rest = idx / DINNER;
  int i = rest & 1023;
  int b = rest >> 10;
  float acc = cb[c];
  #pragma unroll
  for (int k = 0; k < 4; ++k) {
    int ii = i - 3 + k;
    if (ii >= 0)
      acc += cw[c*4 + k] * bf2f(XZ[((size_t)b*NSEQ + permi<DIR>(ii))*1536 + c]);
  }
  Uo[idx] = f2bf(acc / (1.f + __expf(-acc)));
}

// ---------------- fused 4-direction selective scan ----------------
template<int CTRL>
__device__ __forceinline__ float dpp_add(float v){
  int t = __builtin_amdgcn_update_dpp(0, __float_as_int(v), CTRL, 0xf, 0xf, true);
  return v + __int_as_float(t);
}
__device__ __forceinline__ float wave64_reduce_hi(float p){
  p = dpp_add<0x128>(p);
  p = dpp_add<0x124>(p);
  p = dpp_add<0x122>(p);
  p = dpp_add<0x121>(p);
  p = dpp_add<0x142>(p);
  p = dpp_add<0x143>(p);
  return p;              // lanes 48..63 = total
}

// Per-wave structure identical to round-9 proven shape (4 ch/wave, 16 ch/block);
// dir = blockIdx.z -> 4x waves in flight; accumulate via atomicAdd (SACC zeroed).
// __expf (native v_exp) — round-10's exp2f carried libm guard code (+36% VALU).
template<int DIR>
__device__ __forceinline__ void scan_body(
    const u16* __restrict__ xd,   // per-(dir,b) XD rows [1024][152] bf16
    const u16* __restrict__ dt0,  // per-(dir,b) DT rows [1024][768] bf16
    const u16* __restrict__ u0,
    const u16* __restrict__ z0,   // XZbf + b*1024*1536 (u16)
    float* __restrict__ sp0,      // SACC + b*1024*768
    const float* __restrict__ A_log, const float* __restrict__ Dskip, float wgt)
{
  const int lane = threadIdx.x & 63;
  const int wave = threadIdx.x >> 6;
  const int c0 = blockIdx.x*16 + wave*4;
  const float As0 = -__expf(A_log[(c0+0)*DSTATE + lane]);
  const float As1 = -__expf(A_log[(c0+1)*DSTATE + lane]);
  const float As2 = -__expf(A_log[(c0+2)*DSTATE + lane]);
  const float As3 = -__expf(A_log[(c0+3)*DSTATE + lane]);
  const float4 dsk = *(const float4*)(Dskip + c0);
  const u16* dtp = dt0 + c0;
  const u16* up  = u0 + c0;
  const u16* zp  = z0 + DINNER + c0;
  float* sp = sp0 + c0;

#define SLOAD(k, l) { int lr = (l) < 1023 ? (l) : 1023;                     \
    const u16* x2 = xd + (size_t)lr*XW;                                     \
    B##k = bf2f(x2[24+lane]); C##k = bf2f(x2[88+lane]);                     \
    uint2 td = *(const uint2*)(dtp + (size_t)lr*DINNER);                    \
    uint2 ud = *(const uint2*)(up  + (size_t)lr*DINNER);                    \
    t##k = unp4(td); v##k = unp4(ud);                                       \
    uint2 zd = *(const uint2*)(zp + (size_t)permi<DIR>(lr)*1536);           \
    w##k = unp4(zd); }

#define SSTEP(k, l) {                                                       \
    float e;                                                                \
    e = __expf(t##k.x*As0); g0 = e*g0 + (t##k.x*v##k.x)*B##k;               \
    e = __expf(t##k.y*As1); g1 = e*g1 + (t##k.y*v##k.y)*B##k;               \
    e = __expf(t##k.z*As2); g2 = e*g2 + (t##k.z*v##k.z)*B##k;               \
    e = __expf(t##k.w*As3); g3 = e*g3 + (t##k.w*v##k.w)*B##k;               \
    float p0 = wave64_reduce_hi(g0*C##k);                                   \
    float p1 = wave64_reduce_hi(g1*C##k);                                   \
    float p2 = wave64_reduce_hi(g2*C##k);                                   \
    float p3 = wave64_reduce_hi(g3*C##k);                                   \
    if (lane == 63) {                                                       \
      float* o = sp + (size_t)(l)*DINNER;                                   \
      atomicAdd(o+0, wgt*(p0 + v##k.x*dsk.x)*w##k.x);                       \
      atomicAdd(o+1, wgt*(p1 + v##k.y*dsk.y)*w##k.y);                       \
      atomicAdd(o+2, wgt*(p2 + v##k.z*dsk.z)*w##k.z);                       \
      atomicAdd(o+3, wgt*(p3 + v##k.w*dsk.w)*w##k.w); } }

  float B0,C0,B1,C1,B2,C2,B3,C3;
  float4 t0,t1,t2,t3, v0,v1,v2,v3, w0,w1,w2,w3;
  float g0=0.f, g1=0.f, g2=0.f, g3=0.f;
  SLOAD(0,0) SLOAD(1,1) SLOAD(2,2) SLOAD(3,3)
  __builtin_amdgcn_sched_barrier(0);
  for (int l = 0; l < NSEQ; l += 4) {
    SSTEP(0,l)   SLOAD(0,l+4) __builtin_amdgcn_sched_barrier(0);
    SSTEP(1,l+1) SLOAD(1,l+5) __builtin_amdgcn_sched_barrier(0);
    SSTEP(2,l+2) SLOAD(2,l+6) __builtin_amdgcn_sched_barrier(0);
    SSTEP(3,l+3) SLOAD(3,l+7) __builtin_amdgcn_sched_barrier(0);
  }
#undef SLOAD
#undef SSTEP
}

__global__ __launch_bounds__(256) void scan_all_kernel(
    const u16* __restrict__ XD4, const u16* __restrict__ DT4,
    const u16* __restrict__ U4, const u16* __restrict__ XZ,
    const float* __restrict__ A_log, const float* __restrict__ Dskip,
    const float* __restrict__ WR, float* __restrict__ SACC, int b0, int BS)
{
  const int dir = blockIdx.z;
  const int b = blockIdx.y;
  const size_t drb = ((size_t)dir*BS + b) * NSEQ;    // per-dir row base
  const u16* xd = XD4 + drb*XW;
  const u16* dt = DT4 + drb*DINNER;
  const u16* uu = U4  + drb*DINNER;
  const u16* zz = XZ  + (size_t)b*NSEQ*1536;
  float* sp = SACC + (size_t)b*NSEQ*DINNER;
  const float wgt = WR[(b0+b)*4 + dir];
  switch (dir) {
    case 0: scan_body<0>(xd, dt, uu, zz, sp, A_log, Dskip, wgt); break;
    case 1: scan_body<1>(xd, dt, uu, zz, sp, A_log, Dskip, wgt); break;
    case 2: scan_body<2>(xd, dt, uu, zz, sp, A_log, Dskip, wgt); break;
    default: scan_body<3>(xd, dt, uu, zz, sp, A_log, Dskip, wgt); break;
  }
}

// ---------------- windowed attention ----------------
__global__ __launch_bounds__(256) void attn_kernel(const float* __restrict__ QKV, float* __restrict__ O){
  int idx = blockIdx.x*256 + threadIdx.x;
  int tq = idx & 3, h = (idx >> 2) & 3, w = idx >> 4;
  size_t row0 = (size_t)w * 4;
  const float4* qp = (const float4*)(QKV + (row0 + tq)*1152 + h*96);
  float sc[4];
  #pragma unroll
  for (int tk = 0; tk < 4; ++tk) {
    const float4* kp = (const float4*)(QKV + (row0 + tk)*1152 + 384 + h*96);
    float d = 0.f;
    #pragma unroll
    for (int j = 0; j < 24; ++j) {
      float4 qf = qp[j], kf = kp[j];
      d += qf.x*kf.x + qf.y*kf.y + qf.z*kf.z + qf.w*kf.w;
    }
    sc[tk] = d * 0.10206207261596575f;
  }
  float mx = fmaxf(fmaxf(sc[0],sc[1]),fmaxf(sc[2],sc[3]));
  float s = 0.f;
  #pragma unroll
  for (int tk=0;tk<4;++tk){ sc[tk]=__expf(sc[tk]-mx); s+=sc[tk]; }
  float inv = 1.f/s;
  #pragma unroll
  for (int tk=0;tk<4;++tk) sc[tk]*=inv;
  float4* op = (float4*)(O + (row0 + tq)*DMODEL + h*96);
  #pragma unroll 4
  for (int j = 0; j < 24; ++j) {
    float4 o = {0.f,0.f,0.f,0.f};
    #pragma unroll
    for (int tk=0;tk<4;++tk){
      const float4* vp = (const float4*)(QKV + (row0+tk)*1152 + 768 + h*96);
      float4 vf = vp[j];
      o.x += sc[tk]*vf.x; o.y += sc[tk]*vf.y; o.z += sc[tk]*vf.z; o.w += sc[tk]*vf.w;
    }
    op[j] = o;
  }
}

extern "C" void kernel_launch(void* const* d_in, const int* in_sizes, int n_in,
                              void* d_out, int out_size, void* d_ws, size_t ws_size,
                              hipStream_t stream)
{
  (void)in_sizes; (void)n_in; (void)out_size;
  const float* x         = (const float*)d_in[0];
  const float* r_w1      = (const float*)d_in[1];
  const float* r_b1      = (const float*)d_in[2];
  const float* r_w2      = (const float*)d_in[3];
  const float* r_b2      = (const float*)d_in[4];
  const float* ln1_w     = (const float*)d_in[5];
  const float* ln1_b     = (const float*)d_in[6];
  const float* ln2_w     = (const float*)d_in[7];
  const float* ln2_b     = (const float*)d_in[8];
  const float* in_proj_w = (const float*)d_in[9];
  const float* conv_w    = (const float*)d_in[10];
  const float* conv_b    = (const float*)d_in[11];
  const float* x_proj_w  = (const float*)d_in[12];
  const float* dt_proj_w = (const float*)d_in[13];
  const float* dt_proj_b = (const float*)d_in[14];
  const float* A_log     = (const float*)d_in[15];
  const float* D_skip    = (const float*)d_in[16];
  const float* out_proj_w= (const float*)d_in[17];
  const float* qkv_w     = (const float*)d_in[18];
  const float* qkv_b     = (const float*)d_in[19];
  const float* ao_w      = (const float*)d_in[20];
  const float* ao_b      = (const float*)d_in[21];
  const float* gate      = (const float*)d_in[22];
  const float* lng_w     = (const float*)d_in[23];
  const float* lng_b     = (const float*)d_in[24];

  float* ws = (float*)d_ws;
  float* WR = ws;            // 32 floats
  float* G  = ws + 64;       // 3072 floats
  u16*  WBF = (u16*)(ws + 3200);
  u16* ipw = WBF + 0;        // 1536*384
  u16* xpw = WBF + 589824;   // 152*768
  u16* dtw = WBF + 706560;   // 768*24
  u16* opw = WBF + 724992;   // 384*768
  u16* qkw = WBF + 1019904;  // 1152*384
  u16* aow = WBF + 1462272;  // 384*384 (end 1609728 u16 = 804864 fl)

  int BS = 8;
  while (BS > 1) {
    size_t need = ((size_t)808064 + (size_t)BS*1024*5296) * sizeof(float);
    if (need <= ws_size) break;
    BS >>= 1;
  }
  const int R = BS * 1024;

  (void)hipMemsetAsync(ws, 0, 4096*sizeof(float), stream);
  router_mean_kernel<<<dim3(16,8),384,0,stream>>>(x, G);
  router_mlp_kernel<<<8,96,0,stream>>>(G, r_w1, r_b1, r_w2, r_b2, WR);

  cvt4_kernel<<<576,256,0,stream>>>(in_proj_w, ipw, 147456);
  cvt4_kernel<<<114,256,0,stream>>>(x_proj_w,  xpw, 29184);
  cvt4_kernel<<<18,256,0,stream>>>(dt_proj_w,  dtw, 4608);
  cvt4_kernel<<<288,256,0,stream>>>(out_proj_w,opw, 73728);
  cvt4_kernel<<<432,256,0,stream>>>(qkv_w,     qkw, 110592);
  cvt4_kernel<<<144,256,0,stream>>>(ao_w,      aow, 36864);

  float* base = ws + 808064;
  u16*   ABF  = (u16*)base;                        // R*768 u16
  u16*   XZbf = (u16*)(base + (size_t)R*384);      // R*1536 u16
  u16*   Ub4  = (u16*)(base + (size_t)R*1152);     // 4R*768 u16
  u16*   XD4  = (u16*)(base + (size_t)R*2688);     // 4R*152 u16
  u16*   DT4  = (u16*)(base + (size_t)R*2992);     // 4R*768 u16
  float* SACC = base + (size_t)R*4528;             // R*768 f32 (end R*5296)
  // post-scan aliases
  float* X2   = (float*)Ub4;                       // R*384
  float* QKV  = (float*)Ub4 + (size_t)R*384;       // R*1152
  float* XN2  = SACC;                              // R*384
  float* AOb  = SACC + (size_t)R*384;              // R*384
  float* ATTO = (float*)DT4;                       // R*384

  for (int s = 0; s < 8/BS; ++s) {
    const int b0 = s * BS;
    const size_t xoff = (size_t)b0 * NSEQ * DMODEL;

    (void)hipMemsetAsync(SACC, 0, (size_t)R*768*sizeof(float), stream);
    ln_bf16out_kernel<<<R/4,256,0,stream>>>(x + xoff, ln1_w, ln1_b, ABF);
    mgemm_kernel<<<dim3(24,R/256),256,0,stream>>>(ABF,384, ipw,384,1536, nullptr,nullptr,0,1, XZbf,1536);
    zsilu_kernel<<<(R*96)/256,256,0,stream>>>(XZbf);
    conv_silu_kernel<0><<<3*R,256,0,stream>>>(XZbf, conv_w, conv_b, Ub4);
    conv_silu_kernel<1><<<3*R,256,0,stream>>>(XZbf, conv_w, conv_b, Ub4 + (size_t)R*768);
    conv_silu_kernel<2><<<3*R,256,0,stream>>>(XZbf, conv_w, conv_b, Ub4 + (size_t)2*R*768);
    conv_silu_kernel<3><<<3*R,256,0,stream>>>(XZbf, conv_w, conv_b, Ub4 + (size_t)3*R*768);
    // batched over dirs: M = 4R
    mgemm_kernel<<<dim3(3,R/64),256,0,stream>>>(Ub4,768, xpw,768,152, nullptr,nullptr,0,1, XD4,152);
    mgemm_kernel<<<dim3(12,R/64),256,0,stream>>>(XD4,152, dtw,24,768, dt_proj_b,nullptr,1,1, DT4,768);
    scan_all_kernel<<<dim3(48,BS,4),256,0,stream>>>(XD4, DT4, Ub4, XZbf, A_log, D_skip, WR, SACC, b0, BS);
    cvt4_kernel<<<(R*192)/256,256,0,stream>>>(SACC, ABF, R*192);
    mgemm_kernel<<<dim3(6,R/256),256,0,stream>>>(ABF,768, opw,768,384, nullptr,x + xoff,0,0, X2,384);
    ln_kernel<<<R/4,256,0,stream>>>(X2, ln2_w, ln2_b, XN2);
    cvt4_kernel<<<(R*96)/256,256,0,stream>>>(XN2, ABF, R*96);
    mgemm_kernel<<<dim3(18,R/256),256,0,stream>>>(ABF,384, qkw,384,1152, qkv_b,nullptr,0,0, QKV,1152);
    attn_kernel<<<R/64,256,0,stream>>>(QKV, ATTO);
    cvt4_kernel<<<(R*96)/256,256,0,stream>>>(ATTO, ABF, R*96);
    mgemm_kernel<<<dim3(6,R/256),256,0,stream>>>(ABF,384, aow,384,384, ao_b,nullptr,0,0, AOb,384);
    ln_final_kernel<<<R/4,256,0,stream>>>(XN2, AOb, gate, lng_w, lng_b, (float*)d_out + xoff);
  }
}

// Round 12
// 1462.479 us; speedup vs baseline: 2.6029x; 1.3328x over previous
//
#include <hip/hip_runtime.h>
#include <math.h>

// ASMambaBlock: router + 4-dir Mamba (fused concurrent scans, LDS-accumulated)
// + windowed MHA. bf16 MFMA GEMMs. No global atomics: each block owns 8
// channels x 4 dirs, sums dirs in LDS, stores bf16 fused output directly.
// ws floats: WR 0 | G 64 | WBF @3200 | slices @808064.
// Per-slice: ABF R*384 | XZbf R*768 | Ub4 R*1536 | XD4 R*304 | DT4 R*1536
// | XN2 R*384 | AOb R*384 = R*5296 floats. BS=8 -> 176.7 MB (proven), auto-halves.

#define NSEQ  1024
#define DMODEL 384
#define DINNER 768
#define DSTATE 64
#define XW 152
#define SCHUNK 128

typedef unsigned short u16;
typedef __attribute__((ext_vector_type(8))) short short8;
typedef __attribute__((ext_vector_type(4))) float f32x4;

__device__ __forceinline__ float bf2f(u16 u){
  union { unsigned int i; float f; } c; c.i = ((unsigned int)u) << 16; return c.f;
}
__device__ __forceinline__ u16 f2bf(float f){
  union { float f; unsigned int i; } c; c.f = f;
  unsigned int x = c.i;
  return (u16)((x + 0x7fffu + ((x >> 16) & 1u)) >> 16);
}
__device__ __forceinline__ float4 unp4(uint2 u){
  float4 f;
  f.x = bf2f((u16)(u.x & 0xffffu)); f.y = bf2f((u16)(u.x >> 16));
  f.z = bf2f((u16)(u.y & 0xffffu)); f.w = bf2f((u16)(u.y >> 16));
  return f;
}

template<int DIR>
__device__ __forceinline__ int permi(int i){
  if (DIR == 0) return i;
  if (DIR == 1) return ((i & 31) << 5) | (i >> 5);
  if (DIR == 2) return 1023 - i;
  int j = 1023 - i; return ((j & 31) << 5) | (j >> 5);
}

// ---------------- router ----------------
__global__ __launch_bounds__(384) void router_mean_kernel(const float* __restrict__ X, float* __restrict__ G){
  int b = blockIdx.y, chunk = blockIdx.x, c = threadIdx.x;
  float s = 0.f;
  const float* xp = X + ((size_t)b*NSEQ + (size_t)chunk*64)*DMODEL + c;
  for (int l = 0; l < 64; ++l) s += xp[(size_t)l*DMODEL];
  atomicAdd(&G[b*DMODEL + c], s * (1.f/1024.f));
}

__global__ __launch_bounds__(96) void router_mlp_kernel(const float* __restrict__ G,
    const float* __restrict__ w1, const float* __restrict__ b1,
    const float* __restrict__ w2, const float* __restrict__ b2, float* __restrict__ WR){
  int b = blockIdx.x, j = threadIdx.x;
  __shared__ float hs[96];
  __shared__ float ls[4];
  float a = b1[j];
  const float* g = G + b*DMODEL;
  for (int c = 0; c < DMODEL; ++c) a += g[c] * w1[j*DMODEL + c];
  hs[j] = 0.5f * a * (1.f + erff(a * 0.70710678118654752f));
  __syncthreads();
  if (j < 4) {
    float lg = b2[j];
    for (int jj = 0; jj < 96; ++jj) lg += hs[jj] * w2[j*96 + jj];
    ls[j] = lg;
  }
  __syncthreads();
  if (j == 0) {
    float mx = fmaxf(fmaxf(ls[0],ls[1]),fmaxf(ls[2],ls[3]));
    float e0=__expf(ls[0]-mx), e1=__expf(ls[1]-mx), e2=__expf(ls[2]-mx), e3=__expf(ls[3]-mx);
    float s = e0+e1+e2+e3;
    WR[b*4+0]=e0/s; WR[b*4+1]=e1/s; WR[b*4+2]=e2/s; WR[b*4+3]=e3/s;
  }
}

// ---------------- layernorms ----------------
__global__ __launch_bounds__(256) void ln_bf16out_kernel(const float* __restrict__ X,
    const float* __restrict__ w, const float* __restrict__ bb, u16* __restrict__ O){
  int row = blockIdx.x*4 + (threadIdx.x >> 6);
  int lane = threadIdx.x & 63;
  const float* xr = X + (size_t)row*DMODEL;
  float v[6]; float s=0.f, s2=0.f;
  #pragma unroll
  for (int j=0;j<6;++j){ float t = xr[lane + j*64]; v[j]=t; s+=t; s2+=t*t; }
  #pragma unroll
  for (int m=1;m<64;m<<=1){ s += __shfl_xor(s,m,64); s2 += __shfl_xor(s2,m,64); }
  float mu = s*(1.f/DMODEL);
  float rs = rsqrtf(s2*(1.f/DMODEL) - mu*mu + 1e-5f);
  u16* o = O + (size_t)row*DMODEL;
  #pragma unroll
  for (int j=0;j<6;++j){ int i = lane+j*64; o[i] = f2bf((v[j]-mu)*rs*w[i] + bb[i]); }
}

__global__ __launch_bounds__(256) void ln_kernel(const float* __restrict__ X,
    const float* __restrict__ w, const float* __restrict__ bb, float* __restrict__ O){
  int row = blockIdx.x*4 + (threadIdx.x >> 6);
  int lane = threadIdx.x & 63;
  const float* xr = X + (size_t)row*DMODEL;
  float v[6]; float s=0.f, s2=0.f;
  #pragma unroll
  for (int j=0;j<6;++j){ float t = xr[lane + j*64]; v[j]=t; s+=t; s2+=t*t; }
  #pragma unroll
  for (int m=1;m<64;m<<=1){ s += __shfl_xor(s,m,64); s2 += __shfl_xor(s2,m,64); }
  float mu = s*(1.f/DMODEL);
  float rs = rsqrtf(s2*(1.f/DMODEL) - mu*mu + 1e-5f);
  float* o = O + (size_t)row*DMODEL;
  #pragma unroll
  for (int j=0;j<6;++j){ int i = lane+j*64; o[i] = (v[j]-mu)*rs*w[i] + bb[i]; }
}

__global__ __launch_bounds__(256) void ln_final_kernel(const float* __restrict__ XN2,
    const float* __restrict__ AO, const float* __restrict__ gatep,
    const float* __restrict__ w, const float* __restrict__ bb, float* __restrict__ OUT){
  int row = blockIdx.x*4 + (threadIdx.x >> 6);
  int lane = threadIdx.x & 63;
  float gate = gatep[0];
  const float* xr = XN2 + (size_t)row*DMODEL;
  const float* ar = AO + (size_t)row*DMODEL;
  float v[6]; float s=0.f, s2=0.f;
  #pragma unroll
  for (int j=0;j<6;++j){ int i = lane+j*64; float t = xr[i] + gate*ar[i]; v[j]=t; s+=t; s2+=t*t; }
  #pragma unroll
  for (int m=1;m<64;m<<=1){ s += __shfl_xor(s,m,64); s2 += __shfl_xor(s2,m,64); }
  float mu = s*(1.f/DMODEL);
  float rs = rsqrtf(s2*(1.f/DMODEL) - mu*mu + 1e-5f);
  float* o = OUT + (size_t)row*DMODEL;
  #pragma unroll
  for (int j=0;j<6;++j){ int i = lane+j*64; o[i] = (v[j]-mu)*rs*w[i] + bb[i]; }
}

// ---------------- f32 -> bf16 conversion ----------------
__global__ __launch_bounds__(256) void cvt4_kernel(const float* __restrict__ src,
    u16* __restrict__ dst, int n4){
  int i = blockIdx.x*256 + threadIdx.x;
  if (i >= n4) return;
  float4 v = ((const float4*)src)[i];
  ushort4 o; o.x=f2bf(v.x); o.y=f2bf(v.y); o.z=f2bf(v.z); o.w=f2bf(v.w);
  ((ushort4*)dst)[i] = o;
}

// ---------------- bf16 MFMA GEMM ----------------
__global__ __launch_bounds__(256) void mgemm_kernel(
    const u16* __restrict__ A, int lda,
    const u16* __restrict__ W, int K, int N,
    const float* __restrict__ bias,
    const float* __restrict__ resid,
    int act,                 // 0 none, 1 softplus
    int obf,                 // 0: f32 out, 1: bf16 out
    void* __restrict__ C, int ldc)
{
  const int lane = threadIdx.x & 63;
  const int wv = threadIdx.x >> 6;
  const int m0 = (blockIdx.y*4 + wv) * 64;
  const int n0 = blockIdx.x * 64;
  const int r  = lane & 15;
  const int kg = lane >> 4;
  f32x4 acc[4][4];
  #pragma unroll
  for (int i=0;i<4;++i){
    #pragma unroll
    for (int j=0;j<4;++j) acc[i][j] = (f32x4)0.f;
  }
  for (int k0 = 0; k0 < K; k0 += 32) {
    const bool kval = (k0 + kg*8) < K;
    short8 a[4], b[4];
    #pragma unroll
    for (int i = 0; i < 4; ++i) {
      a[i] = kval ? *(const short8*)(A + (size_t)(m0 + i*16 + r)*lda + k0 + kg*8) : (short8)0;
      int n = n0 + i*16 + r;
      b[i] = (kval && n < N) ? *(const short8*)(W + (size_t)n*K + k0 + kg*8) : (short8)0;
    }
    #pragma unroll
    for (int ai = 0; ai < 4; ++ai)
      #pragma unroll
      for (int bi = 0; bi < 4; ++bi)
        acc[ai][bi] = __builtin_amdgcn_mfma_f32_16x16x32_bf16(a[ai], b[bi], acc[ai][bi], 0, 0, 0);
  }
  #pragma unroll
  for (int ai = 0; ai < 4; ++ai) {
    int mrow = m0 + ai*16 + kg*4;
    #pragma unroll
    for (int bi = 0; bi < 4; ++bi) {
      int n = n0 + bi*16 + r;
      if (n < N) {
        #pragma unroll
        for (int q = 0; q < 4; ++q) {
          float v = acc[ai][bi][q];
          int m = mrow + q;
          if (bias) v += bias[n];
          if (act == 1) v = (v > 20.f) ? v : log1pf(__expf(v));
          if (resid) v += resid[(size_t)m*ldc + n];
          if (obf) ((u16*)C)[(size_t)m*ldc + n] = f2bf(v);
          else     ((float*)C)[(size_t)m*ldc + n] = v;
        }
      }
    }
  }
}

// ---------------- in-place silu on z-half of XZbf ----------------
__global__ __launch_bounds__(256) void zsilu_kernel(u16* __restrict__ XZ){
  int idx = blockIdx.x*256 + threadIdx.x;       // R*96 threads, 8 bf16 each
  int row = idx / 96, q = idx % 96;
  u16* p = XZ + (size_t)row*1536 + DINNER + q*8;
  uint4 v = *(uint4*)p;
  unsigned w0=v.x, w1=v.y, w2=v.z, w3=v.w;
  #define ZS(w) { \
    float lo = bf2f((u16)((w) & 0xffffu)); \
    float hi = bf2f((u16)((w) >> 16)); \
    lo = lo / (1.f + __expf(-lo)); \
    hi = hi / (1.f + __expf(-hi)); \
    (w) = (unsigned)f2bf(lo) | ((unsigned)f2bf(hi) << 16); }
  ZS(w0) ZS(w1) ZS(w2) ZS(w3)
  #undef ZS
  v.x=w0; v.y=w1; v.z=w2; v.w=w3;
  *(uint4*)p = v;
}

// ---------------- depthwise causal conv (k=4) + silu, bf16 in/out ----------------
template<int DIR>
__global__ __launch_bounds__(256) void conv_silu_kernel(const u16* __restrict__ XZ,
    const float* __restrict__ cw, const float* __restrict__ cb, u16* __restrict__ Uo){
  int idx = blockIdx.x*256 + threadIdx.x;        // b*1024*768 + i*768 + c
  int c = idx % DINNER;
  int rest = idx / DINNER;
  int i = rest & 1023;
  int b = rest >> 10;
  float acc = cb[c];
  #pragma unroll
  for (int k = 0; k < 4; ++k) {
    int ii = i - 3 + k;
    if (ii >= 0)
      acc += cw[c*4 + k] * bf2f(XZ[((size_t)b*NSEQ + permi<DIR>(ii))*1536 + c]);
  }
  Uo[idx] = f2bf(acc / (1.f + __expf(-acc)));
}

// ---------------- fused 4-direction selective scan, LDS-accumulated ----------------
template<int CTRL>
__device__ __forceinline__ float dpp_add(float v){
  int t = __builtin_amdgcn_update_dpp(0, __float_as_int(v), CTRL, 0xf, 0xf, true);
  return v + __int_as_float(t);
}
__device__ __forceinline__ float wave64_reduce_hi(float p){
  p = dpp_add<0x128>(p);
  p = dpp_add<0x124>(p);
  p = dpp_add<0x122>(p);
  p = dpp_add<0x121>(p);
  p = dpp_add<0x142>(p);
  p = dpp_add<0x143>(p);
  return p;              // lanes 48..63 = total
}

// Block = 512 thr (8 waves) = 8 channels x 4 dirs; wave = one dir's 4 channels,
// lane = state (round-9-proven shape, rotation-4 prefetch). Weighted per-step
// float4 -> LDS [4][SCHUNK][8]; every SCHUNK steps: barrier, 4-dir sum, plain
// bf16 store into ABF (out_proj input). No global atomics, no SACC, no memset.
template<int DIR>
__device__ __forceinline__ void scan_body(
    const u16* __restrict__ xd, const u16* __restrict__ dt0,
    const u16* __restrict__ u0, const u16* __restrict__ z0,
    u16* __restrict__ ob,        // ABF + b*1024*768 + c0 (block channel base)
    float* __restrict__ lacc,    // LDS [4][SCHUNK][8]
    const float* __restrict__ A_log, const float* __restrict__ Dskip,
    float wgt, int c0w, int grp)
{
  const int lane = threadIdx.x & 63;
  const float As0 = -__expf(A_log[(c0w+0)*DSTATE + lane]);
  const float As1 = -__expf(A_log[(c0w+1)*DSTATE + lane]);
  const float As2 = -__expf(A_log[(c0w+2)*DSTATE + lane]);
  const float As3 = -__expf(A_log[(c0w+3)*DSTATE + lane]);
  const float4 dsk = *(const float4*)(Dskip + c0w);
  const u16* dtp = dt0 + c0w;
  const u16* up  = u0 + c0w;
  const u16* zp  = z0 + DINNER + c0w;
  float* lw = lacc + DIR*SCHUNK*8 + grp*4;   // + (l&127)*8

#define SLOAD(k, l) { int lr = (l) < 1023 ? (l) : 1023;                     \
    const u16* x2 = xd + (size_t)lr*XW;                                     \
    B##k = bf2f(x2[24+lane]); C##k = bf2f(x2[88+lane]);                     \
    uint2 td = *(const uint2*)(dtp + (size_t)lr*DINNER);                    \
    uint2 ud = *(const uint2*)(up  + (size_t)lr*DINNER);                    \
    t##k = unp4(td); v##k = unp4(ud);                                       \
    uint2 zd = *(const uint2*)(zp + (size_t)permi<DIR>(lr)*1536);           \
    w##k = unp4(zd); }

#define SSTEP(k, l) {                                                       \
    float e;                                                                \
    e = __expf(t##k.x*As0); g0 = e*g0 + (t##k.x*v##k.x)*B##k;               \
    e = __expf(t##k.y*As1); g1 = e*g1 + (t##k.y*v##k.y)*B##k;               \
    e = __expf(t##k.z*As2); g2 = e*g2 + (t##k.z*v##k.z)*B##k;               \
    e = __expf(t##k.w*As3); g3 = e*g3 + (t##k.w*v##k.w)*B##k;               \
    float p0 = wave64_reduce_hi(g0*C##k);                                   \
    float p1 = wave64_reduce_hi(g1*C##k);                                   \
    float p2 = wave64_reduce_hi(g2*C##k);                                   \
    float p3 = wave64_reduce_hi(g3*C##k);                                   \
    if (lane == 63) {                                                       \
      float4 o;                                                             \
      o.x = wgt*(p0 + v##k.x*dsk.x)*w##k.x;                                 \
      o.y = wgt*(p1 + v##k.y*dsk.y)*w##k.y;                                 \
      o.z = wgt*(p2 + v##k.z*dsk.z)*w##k.z;                                 \
      o.w = wgt*(p3 + v##k.w*dsk.w)*w##k.w;                                 \
      *(float4*)(lw + ((l)&(SCHUNK-1))*8) = o; } }

  float B0,C0,B1,C1,B2,C2,B3,C3;
  float4 t0,t1,t2,t3, v0,v1,v2,v3, w0,w1,w2,w3;
  float g0=0.f, g1=0.f, g2=0.f, g3=0.f;
  SLOAD(0,0) SLOAD(1,1) SLOAD(2,2) SLOAD(3,3)
  __builtin_amdgcn_sched_barrier(0);
  for (int l0 = 0; l0 < NSEQ; l0 += SCHUNK) {
    for (int l = l0; l < l0 + SCHUNK; l += 4) {
      SSTEP(0,l)   SLOAD(0,l+4) __builtin_amdgcn_sched_barrier(0);
      SSTEP(1,l+1) SLOAD(1,l+5) __builtin_amdgcn_sched_barrier(0);
      SSTEP(2,l+2) SLOAD(2,l+6) __builtin_amdgcn_sched_barrier(0);
      SSTEP(3,l+3) SLOAD(3,l+7) __builtin_amdgcn_sched_barrier(0);
    }
    __syncthreads();
    // flush: 512 threads, SCHUNK*8 = 1024 outputs, sum 4 dirs, store bf16
    for (int i = threadIdx.x; i < SCHUNK*8; i += 512) {
      float s = lacc[i] + lacc[SCHUNK*8 + i] + lacc[2*SCHUNK*8 + i] + lacc[3*SCHUNK*8 + i];
      int row = i >> 3, c = i & 7;
      ob[(size_t)(l0 + row)*DINNER + c] = f2bf(s);
    }
    __syncthreads();
  }
#undef SLOAD
#undef SSTEP
}

__global__ __launch_bounds__(512) void scan_all_kernel(
    const u16* __restrict__ XD4, const u16* __restrict__ DT4,
    const u16* __restrict__ U4, const u16* __restrict__ XZ,
    u16* __restrict__ OB,
    const float* __restrict__ A_log, const float* __restrict__ Dskip,
    const float* __restrict__ WR, int b0, int BS)
{
  __shared__ float lacc[4*SCHUNK*8];
  const int bx = blockIdx.x;                  // 0..95
  const int sx = (bx & 7)*12 + (bx >> 3);     // bijective XCD-chunked swizzle (96=8*12)
  const int c0 = sx * 8;                      // block channel base
  const int b = blockIdx.y;
  const int w = threadIdx.x >> 6;
  const int dir = w & 3;
  const int grp = w >> 2;                     // 0..1
  const int c0w = c0 + grp*4;
  const size_t drb = ((size_t)dir*BS + b) * NSEQ;
  const u16* xd = XD4 + drb*XW;
  const u16* dt = DT4 + drb*DINNER;
  const u16* uu = U4  + drb*DINNER;
  const u16* zz = XZ  + (size_t)b*NSEQ*1536;
  u16* ob = OB + (size_t)b*NSEQ*DINNER + c0;
  const float wgt = WR[(b0+b)*4 + dir];
  switch (dir) {
    case 0: scan_body<0>(xd, dt, uu, zz, ob, lacc, A_log, Dskip, wgt, c0w, grp); break;
    case 1: scan_body<1>(xd, dt, uu, zz, ob, lacc, A_log, Dskip, wgt, c0w, grp); break;
    case 2: scan_body<2>(xd, dt, uu, zz, ob, lacc, A_log, Dskip, wgt, c0w, grp); break;
    default: scan_body<3>(xd, dt, uu, zz, ob, lacc, A_log, Dskip, wgt, c0w, grp); break;
  }
}

// ---------------- windowed attention ----------------
__global__ __launch_bounds__(256) void attn_kernel(const float* __restrict__ QKV, float* __restrict__ O){
  int idx = blockIdx.x*256 + threadIdx.x;
  int tq = idx & 3, h = (idx >> 2) & 3, w = idx >> 4;
  size_t row0 = (size_t)w * 4;
  const float4* qp = (const float4*)(QKV + (row0 + tq)*1152 + h*96);
  float sc[4];
  #pragma unroll
  for (int tk = 0; tk < 4; ++tk) {
    const float4* kp = (const float4*)(QKV + (row0 + tk)*1152 + 384 + h*96);
    float d = 0.f;
    #pragma unroll
    for (int j = 0; j < 24; ++j) {
      float4 qf = qp[j], kf = kp[j];
      d += qf.x*kf.x + qf.y*kf.y + qf.z*kf.z + qf.w*kf.w;
    }
    sc[tk] = d * 0.10206207261596575f;
  }
  float mx = fmaxf(fmaxf(sc[0],sc[1]),fmaxf(sc[2],sc[3]));
  float s = 0.f;
  #pragma unroll
  for (int tk=0;tk<4;++tk){ sc[tk]=__expf(sc[tk]-mx); s+=sc[tk]; }
  float inv = 1.f/s;
  #pragma unroll
  for (int tk=0;tk<4;++tk) sc[tk]*=inv;
  float4* op = (float4*)(O + (row0 + tq)*DMODEL + h*96);
  #pragma unroll 4
  for (int j = 0; j < 24; ++j) {
    float4 o = {0.f,0.f,0.f,0.f};
    #pragma unroll
    for (int tk=0;tk<4;++tk){
      const float4* vp = (const float4*)(QKV + (row0+tk)*1152 + 768 + h*96);
      float4 vf = vp[j];
      o.x += sc[tk]*vf.x; o.y += sc[tk]*vf.y; o.z += sc[tk]*vf.z; o.w += sc[tk]*vf.w;
    }
    op[j] = o;
  }
}

extern "C" void kernel_launch(void* const* d_in, const int* in_sizes, int n_in,
                              void* d_out, int out_size, void* d_ws, size_t ws_size,
                              hipStream_t stream)
{
  (void)in_sizes; (void)n_in; (void)out_size;
  const float* x         = (const float*)d_in[0];
  const float* r_w1      = (const float*)d_in[1];
  const float* r_b1      = (const float*)d_in[2];
  const float* r_w2      = (const float*)d_in[3];
  const float* r_b2      = (const float*)d_in[4];
  const float* ln1_w     = (const float*)d_in[5];
  const float* ln1_b     = (const float*)d_in[6];
  const float* ln2_w     = (const float*)d_in[7];
  const float* ln2_b     = (const float*)d_in[8];
  const float* in_proj_w = (const float*)d_in[9];
  const float* conv_w    = (const float*)d_in[10];
  const float* conv_b    = (const float*)d_in[11];
  const float* x_proj_w  = (const float*)d_in[12];
  const float* dt_proj_w = (const float*)d_in[13];
  const float* dt_proj_b = (const float*)d_in[14];
  const float* A_log     = (const float*)d_in[15];
  const float* D_skip    = (const float*)d_in[16];
  const float* out_proj_w= (const float*)d_in[17];
  const float* qkv_w     = (const float*)d_in[18];
  const float* qkv_b     = (const float*)d_in[19];
  const float* ao_w      = (const float*)d_in[20];
  const float* ao_b      = (const float*)d_in[21];
  const float* gate      = (const float*)d_in[22];
  const float* lng_w     = (const float*)d_in[23];
  const float* lng_b     = (const float*)d_in[24];

  float* ws = (float*)d_ws;
  float* WR = ws;            // 32 floats
  float* G  = ws + 64;       // 3072 floats
  u16*  WBF = (u16*)(ws + 3200);
  u16* ipw = WBF + 0;        // 1536*384
  u16* xpw = WBF + 589824;   // 152*768
  u16* dtw = WBF + 706560;   // 768*24
  u16* opw = WBF + 724992;   // 384*768
  u16* qkw = WBF + 1019904;  // 1152*384
  u16* aow = WBF + 1462272;  // 384*384 (end 1609728 u16 = 804864 fl)

  int BS = 8;
  while (BS > 1) {
    size_t need = ((size_t)808064 + (size_t)BS*1024*5296) * sizeof(float);
    if (need <= ws_size) break;
    BS >>= 1;
  }
  const int R = BS * 1024;

  (void)hipMemsetAsync(ws, 0, 4096*sizeof(float), stream);
  router_mean_kernel<<<dim3(16,8),384,0,stream>>>(x, G);
  router_mlp_kernel<<<8,96,0,stream>>>(G, r_w1, r_b1, r_w2, r_b2, WR);

  cvt4_kernel<<<576,256,0,stream>>>(in_proj_w, ipw, 147456);
  cvt4_kernel<<<114,256,0,stream>>>(x_proj_w,  xpw, 29184);
  cvt4_kernel<<<18,256,0,stream>>>(dt_proj_w,  dtw, 4608);
  cvt4_kernel<<<288,256,0,stream>>>(out_proj_w,opw, 73728);
  cvt4_kernel<<<432,256,0,stream>>>(qkv_w,     qkw, 110592);
  cvt4_kernel<<<144,256,0,stream>>>(ao_w,      aow, 36864);

  float* base = ws + 808064;
  u16*   ABF  = (u16*)base;                        // R*768 u16
  u16*   XZbf = (u16*)(base + (size_t)R*384);      // R*1536 u16
  u16*   Ub4  = (u16*)(base + (size_t)R*1152);     // 4R*768 u16
  u16*   XD4  = (u16*)(base + (size_t)R*2688);     // 4R*152 u16
  u16*   DT4  = (u16*)(base + (size_t)R*2992);     // 4R*768 u16
  float* XN2  = base + (size_t)R*4528;             // R*384 f32
  float* AOb  = base + (size_t)R*4912;             // R*384 f32 (end R*5296)
  // post-scan aliases
  float* X2   = (float*)Ub4;                       // R*384
  float* QKV  = (float*)Ub4 + (size_t)R*384;       // R*1152
  float* ATTO = (float*)DT4;                       // R*384

  for (int s = 0; s < 8/BS; ++s) {
    const int b0 = s * BS;
    const size_t xoff = (size_t)b0 * NSEQ * DMODEL;

    ln_bf16out_kernel<<<R/4,256,0,stream>>>(x + xoff, ln1_w, ln1_b, ABF);
    mgemm_kernel<<<dim3(24,R/256),256,0,stream>>>(ABF,384, ipw,384,1536, nullptr,nullptr,0,1, XZbf,1536);
    zsilu_kernel<<<(R*96)/256,256,0,stream>>>(XZbf);
    conv_silu_kernel<0><<<3*R,256,0,stream>>>(XZbf, conv_w, conv_b, Ub4);
    conv_silu_kernel<1><<<3*R,256,0,stream>>>(XZbf, conv_w, conv_b, Ub4 + (size_t)R*768);
    conv_silu_kernel<2><<<3*R,256,0,stream>>>(XZbf, conv_w, conv_b, Ub4 + (size_t)2*R*768);
    conv_silu_kernel<3><<<3*R,256,0,stream>>>(XZbf, conv_w, conv_b, Ub4 + (size_t)3*R*768);
    // batched over dirs: M = 4R
    mgemm_kernel<<<dim3(3,R/64),256,0,stream>>>(Ub4,768, xpw,768,152, nullptr,nullptr,0,1, XD4,152);
    mgemm_kernel<<<dim3(12,R/64),256,0,stream>>>(XD4,152, dtw,24,768, dt_proj_b,nullptr,1,1, DT4,768);
    scan_all_kernel<<<dim3(96,BS),512,0,stream>>>(XD4, DT4, Ub4, XZbf, ABF, A_log, D_skip, WR, b0, BS);
    mgemm_kernel<<<dim3(6,R/256),256,0,stream>>>(ABF,768, opw,768,384, nullptr,x + xoff,0,0, X2,384);
    ln_kernel<<<R/4,256,0,stream>>>(X2, ln2_w, ln2_b, XN2);
    cvt4_kernel<<<(R*96)/256,256,0,stream>>>(XN2, ABF, R*96);
    mgemm_kernel<<<dim3(18,R/256),256,0,stream>>>(ABF,384, qkw,384,1152, qkv_b,nullptr,0,0, QKV,1152);
    attn_kernel<<<R/64,256,0,stream>>>(QKV, ATTO);
    cvt4_kernel<<<(R*96)/256,256,0,stream>>>(ATTO, ABF, R*96);
    mgemm_kernel<<<dim3(6,R/256),256,0,stream>>>(ABF,384, aow,384,384, ao_b,nullptr,0,0, AOb,384);
    ln_final_kernel<<<R/4,256,0,stream>>>(XN2, AOb, gate, lng_w, lng_b, (float*)d_out + xoff);
  }
}

// Round 13
// 1114.125 us; speedup vs baseline: 3.4167x; 1.3127x over previous
//
#include <hip/hip_runtime.h>
#include <math.h>

// ASMambaBlock: router + 4-dir Mamba (fused concurrent scans, LDS-accumulated)
// + windowed MHA. bf16 MFMA GEMMs. Scan mapping: 16 lanes/channel x 4
// states/lane (4-DPP row reduce) -- ~47 insts/step/wave vs 78 for the
// 1-state/lane mapping (round-12 measured 89% VALUBusy = issue-bound).
// ws floats: WR 0 | G 64 | WBF @3200 | slices @808064.
// Per-slice: ABF R*384 | XZbf R*768 | Ub4 R*1536 | XD4 R*304 | DT4 R*1536
// | XN2 R*384 | AOb R*384 = R*5296 floats. BS=8 -> 176.7 MB, auto-halves.

#define NSEQ  1024
#define DMODEL 384
#define DINNER 768
#define DSTATE 64
#define XW 152
#define SCHUNK 128

typedef unsigned short u16;
typedef __attribute__((ext_vector_type(8))) short short8;
typedef __attribute__((ext_vector_type(4))) float f32x4;

__device__ __forceinline__ float bf2f(u16 u){
  union { unsigned int i; float f; } c; c.i = ((unsigned int)u) << 16; return c.f;
}
__device__ __forceinline__ u16 f2bf(float f){
  union { float f; unsigned int i; } c; c.f = f;
  unsigned int x = c.i;
  return (u16)((x + 0x7fffu + ((x >> 16) & 1u)) >> 16);
}
__device__ __forceinline__ float4 unp4(uint2 u){
  float4 f;
  f.x = bf2f((u16)(u.x & 0xffffu)); f.y = bf2f((u16)(u.x >> 16));
  f.z = bf2f((u16)(u.y & 0xffffu)); f.w = bf2f((u16)(u.y >> 16));
  return f;
}

template<int DIR>
__device__ __forceinline__ int permi(int i){
  if (DIR == 0) return i;
  if (DIR == 1) return ((i & 31) << 5) | (i >> 5);
  if (DIR == 2) return 1023 - i;
  int j = 1023 - i; return ((j & 31) << 5) | (j >> 5);
}

// ---------------- router ----------------
__global__ __launch_bounds__(384) void router_mean_kernel(const float* __restrict__ X, float* __restrict__ G){
  int b = blockIdx.y, chunk = blockIdx.x, c = threadIdx.x;
  float s = 0.f;
  const float* xp = X + ((size_t)b*NSEQ + (size_t)chunk*64)*DMODEL + c;
  for (int l = 0; l < 64; ++l) s += xp[(size_t)l*DMODEL];
  atomicAdd(&G[b*DMODEL + c], s * (1.f/1024.f));
}

__global__ __launch_bounds__(96) void router_mlp_kernel(const float* __restrict__ G,
    const float* __restrict__ w1, const float* __restrict__ b1,
    const float* __restrict__ w2, const float* __restrict__ b2, float* __restrict__ WR){
  int b = blockIdx.x, j = threadIdx.x;
  __shared__ float hs[96];
  __shared__ float ls[4];
  float a = b1[j];
  const float* g = G + b*DMODEL;
  for (int c = 0; c < DMODEL; ++c) a += g[c] * w1[j*DMODEL + c];
  hs[j] = 0.5f * a * (1.f + erff(a * 0.70710678118654752f));
  __syncthreads();
  if (j < 4) {
    float lg = b2[j];
    for (int jj = 0; jj < 96; ++jj) lg += hs[jj] * w2[j*96 + jj];
    ls[j] = lg;
  }
  __syncthreads();
  if (j == 0) {
    float mx = fmaxf(fmaxf(ls[0],ls[1]),fmaxf(ls[2],ls[3]));
    float e0=__expf(ls[0]-mx), e1=__expf(ls[1]-mx), e2=__expf(ls[2]-mx), e3=__expf(ls[3]-mx);
    float s = e0+e1+e2+e3;
    WR[b*4+0]=e0/s; WR[b*4+1]=e1/s; WR[b*4+2]=e2/s; WR[b*4+3]=e3/s;
  }
}

// ---------------- layernorms ----------------
__global__ __launch_bounds__(256) void ln_bf16out_kernel(const float* __restrict__ X,
    const float* __restrict__ w, const float* __restrict__ bb, u16* __restrict__ O){
  int row = blockIdx.x*4 + (threadIdx.x >> 6);
  int lane = threadIdx.x & 63;
  const float* xr = X + (size_t)row*DMODEL;
  float v[6]; float s=0.f, s2=0.f;
  #pragma unroll
  for (int j=0;j<6;++j){ float t = xr[lane + j*64]; v[j]=t; s+=t; s2+=t*t; }
  #pragma unroll
  for (int m=1;m<64;m<<=1){ s += __shfl_xor(s,m,64); s2 += __shfl_xor(s2,m,64); }
  float mu = s*(1.f/DMODEL);
  float rs = rsqrtf(s2*(1.f/DMODEL) - mu*mu + 1e-5f);
  u16* o = O + (size_t)row*DMODEL;
  #pragma unroll
  for (int j=0;j<6;++j){ int i = lane+j*64; o[i] = f2bf((v[j]-mu)*rs*w[i] + bb[i]); }
}

__global__ __launch_bounds__(256) void ln_kernel(const float* __restrict__ X,
    const float* __restrict__ w, const float* __restrict__ bb, float* __restrict__ O){
  int row = blockIdx.x*4 + (threadIdx.x >> 6);
  int lane = threadIdx.x & 63;
  const float* xr = X + (size_t)row*DMODEL;
  float v[6]; float s=0.f, s2=0.f;
  #pragma unroll
  for (int j=0;j<6;++j){ float t = xr[lane + j*64]; v[j]=t; s+=t; s2+=t*t; }
  #pragma unroll
  for (int m=1;m<64;m<<=1){ s += __shfl_xor(s,m,64); s2 += __shfl_xor(s2,m,64); }
  float mu = s*(1.f/DMODEL);
  float rs = rsqrtf(s2*(1.f/DMODEL) - mu*mu + 1e-5f);
  float* o = O + (size_t)row*DMODEL;
  #pragma unroll
  for (int j=0;j<6;++j){ int i = lane+j*64; o[i] = (v[j]-mu)*rs*w[i] + bb[i]; }
}

__global__ __launch_bounds__(256) void ln_final_kernel(const float* __restrict__ XN2,
    const float* __restrict__ AO, const float* __restrict__ gatep,
    const float* __restrict__ w, const float* __restrict__ bb, float* __restrict__ OUT){
  int row = blockIdx.x*4 + (threadIdx.x >> 6);
  int lane = threadIdx.x & 63;
  float gate = gatep[0];
  const float* xr = XN2 + (size_t)row*DMODEL;
  const float* ar = AO + (size_t)row*DMODEL;
  float v[6]; float s=0.f, s2=0.f;
  #pragma unroll
  for (int j=0;j<6;++j){ int i = lane+j*64; float t = xr[i] + gate*ar[i]; v[j]=t; s+=t; s2+=t*t; }
  #pragma unroll
  for (int m=1;m<64;m<<=1){ s += __shfl_xor(s,m,64); s2 += __shfl_xor(s2,m,64); }
  float mu = s*(1.f/DMODEL);
  float rs = rsqrtf(s2*(1.f/DMODEL) - mu*mu + 1e-5f);
  float* o = OUT + (size_t)row*DMODEL;
  #pragma unroll
  for (int j=0;j<6;++j){ int i = lane+j*64; o[i] = (v[j]-mu)*rs*w[i] + bb[i]; }
}

// ---------------- f32 -> bf16 conversion ----------------
__global__ __launch_bounds__(256) void cvt4_kernel(const float* __restrict__ src,
    u16* __restrict__ dst, int n4){
  int i = blockIdx.x*256 + threadIdx.x;
  if (i >= n4) return;
  float4 v = ((const float4*)src)[i];
  ushort4 o; o.x=f2bf(v.x); o.y=f2bf(v.y); o.z=f2bf(v.z); o.w=f2bf(v.w);
  ((ushort4*)dst)[i] = o;
}

// ---------------- bf16 MFMA GEMM ----------------
__global__ __launch_bounds__(256) void mgemm_kernel(
    const u16* __restrict__ A, int lda,
    const u16* __restrict__ W, int K, int N,
    const float* __restrict__ bias,
    const float* __restrict__ resid,
    int act,                 // 0 none, 1 softplus
    int obf,                 // 0: f32 out, 1: bf16 out
    void* __restrict__ C, int ldc)
{
  const int lane = threadIdx.x & 63;
  const int wv = threadIdx.x >> 6;
  const int m0 = (blockIdx.y*4 + wv) * 64;
  const int n0 = blockIdx.x * 64;
  const int r  = lane & 15;
  const int kg = lane >> 4;
  f32x4 acc[4][4];
  #pragma unroll
  for (int i=0;i<4;++i){
    #pragma unroll
    for (int j=0;j<4;++j) acc[i][j] = (f32x4)0.f;
  }
  for (int k0 = 0; k0 < K; k0 += 32) {
    const bool kval = (k0 + kg*8) < K;
    short8 a[4], b[4];
    #pragma unroll
    for (int i = 0; i < 4; ++i) {
      a[i] = kval ? *(const short8*)(A + (size_t)(m0 + i*16 + r)*lda + k0 + kg*8) : (short8)0;
      int n = n0 + i*16 + r;
      b[i] = (kval && n < N) ? *(const short8*)(W + (size_t)n*K + k0 + kg*8) : (short8)0;
    }
    #pragma unroll
    for (int ai = 0; ai < 4; ++ai)
      #pragma unroll
      for (int bi = 0; bi < 4; ++bi)
        acc[ai][bi] = __builtin_amdgcn_mfma_f32_16x16x32_bf16(a[ai], b[bi], acc[ai][bi], 0, 0, 0);
  }
  #pragma unroll
  for (int ai = 0; ai < 4; ++ai) {
    int mrow = m0 + ai*16 + kg*4;
    #pragma unroll
    for (int bi = 0; bi < 4; ++bi) {
      int n = n0 + bi*16 + r;
      if (n < N) {
        #pragma unroll
        for (int q = 0; q < 4; ++q) {
          float v = acc[ai][bi][q];
          int m = mrow + q;
          if (bias) v += bias[n];
          if (act == 1) v = (v > 20.f) ? v : log1pf(__expf(v));
          if (resid) v += resid[(size_t)m*ldc + n];
          if (obf) ((u16*)C)[(size_t)m*ldc + n] = f2bf(v);
          else     ((float*)C)[(size_t)m*ldc + n] = v;
        }
      }
    }
  }
}

// ---------------- in-place silu on z-half of XZbf ----------------
__global__ __launch_bounds__(256) void zsilu_kernel(u16* __restrict__ XZ){
  int idx = blockIdx.x*256 + threadIdx.x;       // R*96 threads, 8 bf16 each
  int row = idx / 96, q = idx % 96;
  u16* p = XZ + (size_t)row*1536 + DINNER + q*8;
  uint4 v = *(uint4*)p;
  unsigned w0=v.x, w1=v.y, w2=v.z, w3=v.w;
  #define ZS(w) { \
    float lo = bf2f((u16)((w) & 0xffffu)); \
    float hi = bf2f((u16)((w) >> 16)); \
    lo = lo / (1.f + __expf(-lo)); \
    hi = hi / (1.f + __expf(-hi)); \
    (w) = (unsigned)f2bf(lo) | ((unsigned)f2bf(hi) << 16); }
  ZS(w0) ZS(w1) ZS(w2) ZS(w3)
  #undef ZS
  v.x=w0; v.y=w1; v.z=w2; v.w=w3;
  *(uint4*)p = v;
}

// ---------------- depthwise causal conv (k=4) + silu, bf16 in/out ----------------
template<int DIR>
__global__ __launch_bounds__(256) void conv_silu_kernel(const u16* __restrict__ XZ,
    const float* __restrict__ cw, const float* __restrict__ cb, u16* __restrict__ Uo){
  int idx = blockIdx.x*256 + threadIdx.x;        // b*1024*768 + i*768 + c
  int c = idx % DINNER;
  int rest = idx / DINNER;
  int i = rest & 1023;
  int b = rest >> 10;
  float acc = cb[c];
  #pragma unroll
  for (int k = 0; k < 4; ++k) {
    int ii = i - 3 + k;
    if (ii >= 0)
      acc += cw[c*4 + k] * bf2f(XZ[((size_t)b*NSEQ + permi<DIR>(ii))*1536 + c]);
  }
  Uo[idx] = f2bf(acc / (1.f + __expf(-acc)));
}

// ---------------- fused 4-direction selective scan, LDS-accumulated ----------------
template<int CTRL>
__device__ __forceinline__ float dpp_add(float v){
  int t = __builtin_amdgcn_update_dpp(0, __float_as_int(v), CTRL, 0xf, 0xf, true);
  return v + __int_as_float(t);
}
__device__ __forceinline__ float row16_sum(float p){
  p = dpp_add<0x128>(p); // row_ror 8
  p = dpp_add<0x124>(p); // row_ror 4
  p = dpp_add<0x122>(p); // row_ror 2
  p = dpp_add<0x121>(p); // row_ror 1 -> every lane of each 16-row has the row sum
  return p;
}

// Block = 512 thr (8 waves) = 8 channels x 4 dirs. Wave = one dir's 4 channels,
// mapped 16 lanes/channel x 4 states/lane (4-DPP reduce). Rotation-4 prefetch.
// Weighted per-step outputs -> LDS [4][SCHUNK][8]; flush every SCHUNK steps to
// bf16 ABF. No global atomics.
template<int DIR>
__device__ __forceinline__ void scan_body(
    const u16* __restrict__ xd, const u16* __restrict__ dt0,
    const u16* __restrict__ u0, const u16* __restrict__ z0,
    u16* __restrict__ ob,        // ABF + b*1024*768 + c0 (block channel base)
    float* __restrict__ lacc,    // LDS [4][SCHUNK][8]
    const float* __restrict__ A_log, const float* __restrict__ Dskip,
    float wgt, int c0w, int grp)
{
  const int lane = threadIdx.x & 63;
  const int g = lane >> 4;            // channel within wave (0..3)
  const int q = lane & 15;            // state quarter: states q*4..q*4+3
  const int c = c0w + g;              // global channel
  const float4 Alq = *(const float4*)(A_log + (size_t)c*DSTATE + q*4);
  const float As0 = -__expf(Alq.x), As1 = -__expf(Alq.y);
  const float As2 = -__expf(Alq.z), As3 = -__expf(Alq.w);
  const float dsk = Dskip[c];
  const u16* dtp = dt0 + c;
  const u16* up  = u0 + c;
  const u16* zp  = z0 + DINNER + c;
  float* lw = lacc + DIR*SCHUNK*8 + grp*4 + g;   // + (l&127)*8

#define SLOAD(k, l) { int lr = (l) < 1023 ? (l) : 1023;                     \
    const u16* x2 = xd + (size_t)lr*XW;                                     \
    uint2 bd = *(const uint2*)(x2 + 24 + q*4);                              \
    uint2 cd = *(const uint2*)(x2 + 88 + q*4);                              \
    B##k = unp4(bd); C##k = unp4(cd);                                       \
    t##k = bf2f(dtp[(size_t)lr*DINNER]);                                    \
    u##k = bf2f(up [(size_t)lr*DINNER]);                                    \
    z##k = bf2f(zp [(size_t)permi<DIR>(lr)*1536]); }

#define SSTEP(k, l) {                                                       \
    float dtu = t##k * u##k;                                                \
    float e0 = __expf(t##k*As0), e1 = __expf(t##k*As1);                     \
    float e2 = __expf(t##k*As2), e3 = __expf(t##k*As3);                     \
    h0 = e0*h0 + dtu*B##k.x; h1 = e1*h1 + dtu*B##k.y;                       \
    h2 = e2*h2 + dtu*B##k.z; h3 = e3*h3 + dtu*B##k.w;                       \
    float p = h0*C##k.x + h1*C##k.y + h2*C##k.z + h3*C##k.w;                \
    p = row16_sum(p);                                                       \
    float o = wgt*(p + u##k*dsk)*z##k;                                      \
    if (q == 0) lw[((l)&(SCHUNK-1))*8] = o; }

  float4 B0,C0,B1,C1,B2,C2,B3,C3;
  float t0,u0_,z0_, t1,u1,z1, t2,u2,z2, t3,u3,z3;
  #define u0 u0_
  #define z0 z0_
  float h0=0.f, h1=0.f, h2=0.f, h3=0.f;
  SLOAD(0,0) SLOAD(1,1) SLOAD(2,2) SLOAD(3,3)
  __builtin_amdgcn_sched_barrier(0);
  for (int l0 = 0; l0 < NSEQ; l0 += SCHUNK) {
    for (int l = l0; l < l0 + SCHUNK; l += 4) {
      SSTEP(0,l)   SLOAD(0,l+4) __builtin_amdgcn_sched_barrier(0);
      SSTEP(1,l+1) SLOAD(1,l+5) __builtin_amdgcn_sched_barrier(0);
      SSTEP(2,l+2) SLOAD(2,l+6) __builtin_amdgcn_sched_barrier(0);
      SSTEP(3,l+3) SLOAD(3,l+7) __builtin_amdgcn_sched_barrier(0);
    }
    __syncthreads();
    // flush: 512 threads, SCHUNK*8 = 1024 outputs, sum 4 dirs, store bf16
    for (int i = threadIdx.x; i < SCHUNK*8; i += 512) {
      float s = lacc[i] + lacc[SCHUNK*8 + i] + lacc[2*SCHUNK*8 + i] + lacc[3*SCHUNK*8 + i];
      int row = i >> 3, cc = i & 7;
      ob[(size_t)(l0 + row)*DINNER + cc] = f2bf(s);
    }
    __syncthreads();
  }
#undef u0
#undef z0
#undef SLOAD
#undef SSTEP
}

__global__ __launch_bounds__(512) void scan_all_kernel(
    const u16* __restrict__ XD4, const u16* __restrict__ DT4,
    const u16* __restrict__ U4, const u16* __restrict__ XZ,
    u16* __restrict__ OB,
    const float* __restrict__ A_log, const float* __restrict__ Dskip,
    const float* __restrict__ WR, int b0, int BS)
{
  __shared__ float lacc[4*SCHUNK*8];
  const int bx = blockIdx.x;                  // 0..95
  const int sx = (bx & 7)*12 + (bx >> 3);     // bijective XCD-chunked swizzle (96=8*12)
  const int c0 = sx * 8;                      // block channel base
  const int b = blockIdx.y;
  const int w = threadIdx.x >> 6;
  const int dir = w & 3;
  const int grp = w >> 2;                     // 0..1
  const int c0w = c0 + grp*4;
  const size_t drb = ((size_t)dir*BS + b) * NSEQ;
  const u16* xd = XD4 + drb*XW;
  const u16* dt = DT4 + drb*DINNER;
  const u16* uu = U4  + drb*DINNER;
  const u16* zz = XZ  + (size_t)b*NSEQ*1536;
  u16* ob = OB + (size_t)b*NSEQ*DINNER + c0;
  const float wgt = WR[(b0+b)*4 + dir];
  switch (dir) {
    case 0: scan_body<0>(xd, dt, uu, zz, ob, lacc, A_log, Dskip, wgt, c0w, grp); break;
    case 1: scan_body<1>(xd, dt, uu, zz, ob, lacc, A_log, Dskip, wgt, c0w, grp); break;
    case 2: scan_body<2>(xd, dt, uu, zz, ob, lacc, A_log, Dskip, wgt, c0w, grp); break;
    default: scan_body<3>(xd, dt, uu, zz, ob, lacc, A_log, Dskip, wgt, c0w, grp); break;
  }
}

// ---------------- windowed attention ----------------
__global__ __launch_bounds__(256) void attn_kernel(const float* __restrict__ QKV, float* __restrict__ O){
  int idx = blockIdx.x*256 + threadIdx.x;
  int tq = idx & 3, h = (idx >> 2) & 3, w = idx >> 4;
  size_t row0 = (size_t)w * 4;
  const float4* qp = (const float4*)(QKV + (row0 + tq)*1152 + h*96);
  float sc[4];
  #pragma unroll
  for (int tk = 0; tk < 4; ++tk) {
    const float4* kp = (const float4*)(QKV + (row0 + tk)*1152 + 384 + h*96);
    float d = 0.f;
    #pragma unroll
    for (int j = 0; j < 24; ++j) {
      float4 qf = qp[j], kf = kp[j];
      d += qf.x*kf.x + qf.y*kf.y + qf.z*kf.z + qf.w*kf.w;
    }
    sc[tk] = d * 0.10206207261596575f;
  }
  float mx = fmaxf(fmaxf(sc[0],sc[1]),fmaxf(sc[2],sc[3]));
  float s = 0.f;
  #pragma unroll
  for (int tk=0;tk<4;++tk){ sc[tk]=__expf(sc[tk]-mx); s+=sc[tk]; }
  float inv = 1.f/s;
  #pragma unroll
  for (int tk=0;tk<4;++tk) sc[tk]*=inv;
  float4* op = (float4*)(O + (row0 + tq)*DMODEL + h*96);
  #pragma unroll 4
  for (int j = 0; j < 24; ++j) {
    float4 o = {0.f,0.f,0.f,0.f};
    #pragma unroll
    for (int tk=0;tk<4;++tk){
      const float4* vp = (const float4*)(QKV + (row0+tk)*1152 + 768 + h*96);
      float4 vf = vp[j];
      o.x += sc[tk]*vf.x; o.y += sc[tk]*vf.y; o.z += sc[tk]*vf.z; o.w += sc[tk]*vf.w;
    }
    op[j] = o;
  }
}

extern "C" void kernel_launch(void* const* d_in, const int* in_sizes, int n_in,
                              void* d_out, int out_size, void* d_ws, size_t ws_size,
                              hipStream_t stream)
{
  (void)in_sizes; (void)n_in; (void)out_size;
  const float* x         = (const float*)d_in[0];
  const float* r_w1      = (const float*)d_in[1];
  const float* r_b1      = (const float*)d_in[2];
  const float* r_w2      = (const float*)d_in[3];
  const float* r_b2      = (const float*)d_in[4];
  const float* ln1_w     = (const float*)d_in[5];
  const float* ln1_b     = (const float*)d_in[6];
  const float* ln2_w     = (const float*)d_in[7];
  const float* ln2_b     = (const float*)d_in[8];
  const float* in_proj_w = (const float*)d_in[9];
  const float* conv_w    = (const float*)d_in[10];
  const float* conv_b    = (const float*)d_in[11];
  const float* x_proj_w  = (const float*)d_in[12];
  const float* dt_proj_w = (const float*)d_in[13];
  const float* dt_proj_b = (const float*)d_in[14];
  const float* A_log     = (const float*)d_in[15];
  const float* D_skip    = (const float*)d_in[16];
  const float* out_proj_w= (const float*)d_in[17];
  const float* qkv_w     = (const float*)d_in[18];
  const float* qkv_b     = (const float*)d_in[19];
  const float* ao_w      = (const float*)d_in[20];
  const float* ao_b      = (const float*)d_in[21];
  const float* gate      = (const float*)d_in[22];
  const float* lng_w     = (const float*)d_in[23];
  const float* lng_b     = (const float*)d_in[24];

  float* ws = (float*)d_ws;
  float* WR = ws;            // 32 floats
  float* G  = ws + 64;       // 3072 floats
  u16*  WBF = (u16*)(ws + 3200);
  u16* ipw = WBF + 0;        // 1536*384
  u16* xpw = WBF + 589824;   // 152*768
  u16* dtw = WBF + 706560;   // 768*24
  u16* opw = WBF + 724992;   // 384*768
  u16* qkw = WBF + 1019904;  // 1152*384
  u16* aow = WBF + 1462272;  // 384*384 (end 1609728 u16 = 804864 fl)

  int BS = 8;
  while (BS > 1) {
    size_t need = ((size_t)808064 + (size_t)BS*1024*5296) * sizeof(float);
    if (need <= ws_size) break;
    BS >>= 1;
  }
  const int R = BS * 1024;

  (void)hipMemsetAsync(ws, 0, 4096*sizeof(float), stream);
  router_mean_kernel<<<dim3(16,8),384,0,stream>>>(x, G);
  router_mlp_kernel<<<8,96,0,stream>>>(G, r_w1, r_b1, r_w2, r_b2, WR);

  cvt4_kernel<<<576,256,0,stream>>>(in_proj_w, ipw, 147456);
  cvt4_kernel<<<114,256,0,stream>>>(x_proj_w,  xpw, 29184);
  cvt4_kernel<<<18,256,0,stream>>>(dt_proj_w,  dtw, 4608);
  cvt4_kernel<<<288,256,0,stream>>>(out_proj_w,opw, 73728);
  cvt4_kernel<<<432,256,0,stream>>>(qkv_w,     qkw, 110592);
  cvt4_kernel<<<144,256,0,stream>>>(ao_w,      aow, 36864);

  float* base = ws + 808064;
  u16*   ABF  = (u16*)base;                        // R*768 u16
  u16*   XZbf = (u16*)(base + (size_t)R*384);      // R*1536 u16
  u16*   Ub4  = (u16*)(base + (size_t)R*1152);     // 4R*768 u16
  u16*   XD4  = (u16*)(base + (size_t)R*2688);     // 4R*152 u16
  u16*   DT4  = (u16*)(base + (size_t)R*2992);     // 4R*768 u16
  float* XN2  = base + (size_t)R*4528;             // R*384 f32
  float* AOb  = base + (size_t)R*4912;             // R*384 f32 (end R*5296)
  // post-scan aliases
  float* X2   = (float*)Ub4;                       // R*384
  float* QKV  = (float*)Ub4 + (size_t)R*384;       // R*1152
  float* ATTO = (float*)DT4;                       // R*384

  for (int s = 0; s < 8/BS; ++s) {
    const int b0 = s * BS;
    const size_t xoff = (size_t)b0 * NSEQ * DMODEL;

    ln_bf16out_kernel<<<R/4,256,0,stream>>>(x + xoff, ln1_w, ln1_b, ABF);
    mgemm_kernel<<<dim3(24,R/256),256,0,stream>>>(ABF,384, ipw,384,1536, nullptr,nullptr,0,1, XZbf,1536);
    zsilu_kernel<<<(R*96)/256,256,0,stream>>>(XZbf);
    conv_silu_kernel<0><<<3*R,256,0,stream>>>(XZbf, conv_w, conv_b, Ub4);
    conv_silu_kernel<1><<<3*R,256,0,stream>>>(XZbf, conv_w, conv_b, Ub4 + (size_t)R*768);
    conv_silu_kernel<2><<<3*R,256,0,stream>>>(XZbf, conv_w, conv_b, Ub4 + (size_t)2*R*768);
    conv_silu_kernel<3><<<3*R,256,0,stream>>>(XZbf, conv_w, conv_b, Ub4 + (size_t)3*R*768);
    // batched over dirs: M = 4R
    mgemm_kernel<<<dim3(3,R/64),256,0,stream>>>(Ub4,768, xpw,768,152, nullptr,nullptr,0,1, XD4,152);
    mgemm_kernel<<<dim3(12,R/64),256,0,stream>>>(XD4,152, dtw,24,768, dt_proj_b,nullptr,1,1, DT4,768);
    scan_all_kernel<<<dim3(96,BS),512,0,stream>>>(XD4, DT4, Ub4, XZbf, ABF, A_log, D_skip, WR, b0, BS);
    mgemm_kernel<<<dim3(6,R/256),256,0,stream>>>(ABF,768, opw,768,384, nullptr,x + xoff,0,0, X2,384);
    ln_kernel<<<R/4,256,0,stream>>>(X2, ln2_w, ln2_b, XN2);
    cvt4_kernel<<<(R*96)/256,256,0,stream>>>(XN2, ABF, R*96);
    mgemm_kernel<<<dim3(18,R/256),256,0,stream>>>(ABF,384, qkw,384,1152, qkv_b,nullptr,0,0, QKV,1152);
    attn_kernel<<<R/64,256,0,stream>>>(QKV, ATTO);
    cvt4_kernel<<<(R*96)/256,256,0,stream>>>(ATTO, ABF, R*96);
    mgemm_kernel<<<dim3(6,R/256),256,0,stream>>>(ABF,384, aow,384,384, ao_b,nullptr,0,0, AOb,384);
    ln_final_kernel<<<R/4,256,0,stream>>>(XN2, AOb, gate, lng_w, lng_b, (float*)d_out + xoff);
  }
}

// Round 14
// 1089.421 us; speedup vs baseline: 3.4942x; 1.0227x over previous
//
#include <hip/hip_runtime.h>
#include <math.h>

// ASMambaBlock: router + 4-dir Mamba (fused concurrent scans, LDS-accumulated)
// + windowed MHA. bf16 MFMA GEMMs. Scan: 16 lanes/channel x 4 states/lane,
// pointer-increment addressing (round-13 was addressing-bound at 85% VALU).
// dt|u interleaved in UD4[row][1536] so one address serves both (offset imm).
// ws floats: WR 0 | G 64 | WBF @3200 | slices @808064.
// Per-slice: ABF R*384 | XZbf R*768 | UD4 R*3072 | XD4 R*304 | XN2 R*384
// | AOb R*384 = R*5296 floats. BS=8 -> 176.7 MB, auto-halves.
// Buffer order makes all scan prefetch overruns read-only hits inside ws.

#define NSEQ  1024
#define DMODEL 384
#define DINNER 768
#define DSTATE 64
#define XW 152
#define SCHUNK 128

typedef unsigned short u16;
typedef __attribute__((ext_vector_type(8))) short short8;
typedef __attribute__((ext_vector_type(4))) float f32x4;

__device__ __forceinline__ float bf2f(u16 u){
  union { unsigned int i; float f; } c; c.i = ((unsigned int)u) << 16; return c.f;
}
__device__ __forceinline__ u16 f2bf(float f){
  union { float f; unsigned int i; } c; c.f = f;
  unsigned int x = c.i;
  return (u16)((x + 0x7fffu + ((x >> 16) & 1u)) >> 16);
}
__device__ __forceinline__ float4 unp4(uint2 u){
  float4 f;
  f.x = bf2f((u16)(u.x & 0xffffu)); f.y = bf2f((u16)(u.x >> 16));
  f.z = bf2f((u16)(u.y & 0xffffu)); f.w = bf2f((u16)(u.y >> 16));
  return f;
}

template<int DIR>
__device__ __forceinline__ int permi(int i){
  if (DIR == 0) return i;
  if (DIR == 1) return ((i & 31) << 5) | (i >> 5);
  if (DIR == 2) return 1023 - i;
  int j = 1023 - i; return ((j & 31) << 5) | (j >> 5);
}
// incremental form of permi over l -> l+4 (verified against closed form)
template<int DIR>
__device__ __forceinline__ int znext(int zi){
  if (DIR == 0) return zi + 4;
  if (DIR == 2) return zi - 4;
  if (DIR == 1) { int t = zi + 128; return (t >= 1024) ? t - 1023 : t; }
  int t = zi - 128; return (t < 0) ? t + 1023 : t;
}

// ---------------- router ----------------
__global__ __launch_bounds__(384) void router_mean_kernel(const float* __restrict__ X, float* __restrict__ G){
  int b = blockIdx.y, chunk = blockIdx.x, c = threadIdx.x;
  float s = 0.f;
  const float* xp = X + ((size_t)b*NSEQ + (size_t)chunk*64)*DMODEL + c;
  for (int l = 0; l < 64; ++l) s += xp[(size_t)l*DMODEL];
  atomicAdd(&G[b*DMODEL + c], s * (1.f/1024.f));
}

__global__ __launch_bounds__(96) void router_mlp_kernel(const float* __restrict__ G,
    const float* __restrict__ w1, const float* __restrict__ b1,
    const float* __restrict__ w2, const float* __restrict__ b2, float* __restrict__ WR){
  int b = blockIdx.x, j = threadIdx.x;
  __shared__ float hs[96];
  __shared__ float ls[4];
  float a = b1[j];
  const float* g = G + b*DMODEL;
  for (int c = 0; c < DMODEL; ++c) a += g[c] * w1[j*DMODEL + c];
  hs[j] = 0.5f * a * (1.f + erff(a * 0.70710678118654752f));
  __syncthreads();
  if (j < 4) {
    float lg = b2[j];
    for (int jj = 0; jj < 96; ++jj) lg += hs[jj] * w2[j*96 + jj];
    ls[j] = lg;
  }
  __syncthreads();
  if (j == 0) {
    float mx = fmaxf(fmaxf(ls[0],ls[1]),fmaxf(ls[2],ls[3]));
    float e0=__expf(ls[0]-mx), e1=__expf(ls[1]-mx), e2=__expf(ls[2]-mx), e3=__expf(ls[3]-mx);
    float s = e0+e1+e2+e3;
    WR[b*4+0]=e0/s; WR[b*4+1]=e1/s; WR[b*4+2]=e2/s; WR[b*4+3]=e3/s;
  }
}

// ---------------- layernorms ----------------
__global__ __launch_bounds__(256) void ln_bf16out_kernel(const float* __restrict__ X,
    const float* __restrict__ w, const float* __restrict__ bb, u16* __restrict__ O){
  int row = blockIdx.x*4 + (threadIdx.x >> 6);
  int lane = threadIdx.x & 63;
  const float* xr = X + (size_t)row*DMODEL;
  float v[6]; float s=0.f, s2=0.f;
  #pragma unroll
  for (int j=0;j<6;++j){ float t = xr[lane + j*64]; v[j]=t; s+=t; s2+=t*t; }
  #pragma unroll
  for (int m=1;m<64;m<<=1){ s += __shfl_xor(s,m,64); s2 += __shfl_xor(s2,m,64); }
  float mu = s*(1.f/DMODEL);
  float rs = rsqrtf(s2*(1.f/DMODEL) - mu*mu + 1e-5f);
  u16* o = O + (size_t)row*DMODEL;
  #pragma unroll
  for (int j=0;j<6;++j){ int i = lane+j*64; o[i] = f2bf((v[j]-mu)*rs*w[i] + bb[i]); }
}

// ln2: dual output (f32 for ln_final residual path, bf16 for qkv GEMM input)
__global__ __launch_bounds__(256) void ln_dual_kernel(const float* __restrict__ X,
    const float* __restrict__ w, const float* __restrict__ bb,
    float* __restrict__ O, u16* __restrict__ OB){
  int row = blockIdx.x*4 + (threadIdx.x >> 6);
  int lane = threadIdx.x & 63;
  const float* xr = X + (size_t)row*DMODEL;
  float v[6]; float s=0.f, s2=0.f;
  #pragma unroll
  for (int j=0;j<6;++j){ float t = xr[lane + j*64]; v[j]=t; s+=t; s2+=t*t; }
  #pragma unroll
  for (int m=1;m<64;m<<=1){ s += __shfl_xor(s,m,64); s2 += __shfl_xor(s2,m,64); }
  float mu = s*(1.f/DMODEL);
  float rs = rsqrtf(s2*(1.f/DMODEL) - mu*mu + 1e-5f);
  float* o = O + (size_t)row*DMODEL;
  u16* ob = OB + (size_t)row*DMODEL;
  #pragma unroll
  for (int j=0;j<6;++j){ int i = lane+j*64; float r = (v[j]-mu)*rs*w[i] + bb[i]; o[i] = r; ob[i] = f2bf(r); }
}

__global__ __launch_bounds__(256) void ln_final_kernel(const float* __restrict__ XN2,
    const float* __restrict__ AO, const float* __restrict__ gatep,
    const float* __restrict__ w, const float* __restrict__ bb, float* __restrict__ OUT){
  int row = blockIdx.x*4 + (threadIdx.x >> 6);
  int lane = threadIdx.x & 63;
  float gate = gatep[0];
  const float* xr = XN2 + (size_t)row*DMODEL;
  const float* ar = AO + (size_t)row*DMODEL;
  float v[6]; float s=0.f, s2=0.f;
  #pragma unroll
  for (int j=0;j<6;++j){ int i = lane+j*64; float t = xr[i] + gate*ar[i]; v[j]=t; s+=t; s2+=t*t; }
  #pragma unroll
  for (int m=1;m<64;m<<=1){ s += __shfl_xor(s,m,64); s2 += __shfl_xor(s2,m,64); }
  float mu = s*(1.f/DMODEL);
  float rs = rsqrtf(s2*(1.f/DMODEL) - mu*mu + 1e-5f);
  float* o = OUT + (size_t)row*DMODEL;
  #pragma unroll
  for (int j=0;j<6;++j){ int i = lane+j*64; o[i] = (v[j]-mu)*rs*w[i] + bb[i]; }
}

// ---------------- f32 -> bf16 conversion (weights only) ----------------
__global__ __launch_bounds__(256) void cvt4_kernel(const float* __restrict__ src,
    u16* __restrict__ dst, int n4){
  int i = blockIdx.x*256 + threadIdx.x;
  if (i >= n4) return;
  float4 v = ((const float4*)src)[i];
  ushort4 o; o.x=f2bf(v.x); o.y=f2bf(v.y); o.z=f2bf(v.z); o.w=f2bf(v.w);
  ((ushort4*)dst)[i] = o;
}

// ---------------- bf16 MFMA GEMM ----------------
__global__ __launch_bounds__(256) void mgemm_kernel(
    const u16* __restrict__ A, int lda,
    const u16* __restrict__ W, int K, int N,
    const float* __restrict__ bias,
    const float* __restrict__ resid,
    int act,                 // 0 none, 1 softplus
    int obf,                 // 0: f32 out, 1: bf16 out
    void* __restrict__ C, int ldc)
{
  const int lane = threadIdx.x & 63;
  const int wv = threadIdx.x >> 6;
  const int m0 = (blockIdx.y*4 + wv) * 64;
  const int n0 = blockIdx.x * 64;
  const int r  = lane & 15;
  const int kg = lane >> 4;
  f32x4 acc[4][4];
  #pragma unroll
  for (int i=0;i<4;++i){
    #pragma unroll
    for (int j=0;j<4;++j) acc[i][j] = (f32x4)0.f;
  }
  for (int k0 = 0; k0 < K; k0 += 32) {
    const bool kval = (k0 + kg*8) < K;
    short8 a[4], b[4];
    #pragma unroll
    for (int i = 0; i < 4; ++i) {
      a[i] = kval ? *(const short8*)(A + (size_t)(m0 + i*16 + r)*lda + k0 + kg*8) : (short8)0;
      int n = n0 + i*16 + r;
      b[i] = (kval && n < N) ? *(const short8*)(W + (size_t)n*K + k0 + kg*8) : (short8)0;
    }
    #pragma unroll
    for (int ai = 0; ai < 4; ++ai)
      #pragma unroll
      for (int bi = 0; bi < 4; ++bi)
        acc[ai][bi] = __builtin_amdgcn_mfma_f32_16x16x32_bf16(a[ai], b[bi], acc[ai][bi], 0, 0, 0);
  }
  #pragma unroll
  for (int ai = 0; ai < 4; ++ai) {
    int mrow = m0 + ai*16 + kg*4;
    #pragma unroll
    for (int bi = 0; bi < 4; ++bi) {
      int n = n0 + bi*16 + r;
      if (n < N) {
        #pragma unroll
        for (int q = 0; q < 4; ++q) {
          float v = acc[ai][bi][q];
          int m = mrow + q;
          if (bias) v += bias[n];
          if (act == 1) v = (v > 20.f) ? v : log1pf(__expf(v));
          if (resid) v += resid[(size_t)m*ldc + n];
          if (obf) ((u16*)C)[(size_t)m*ldc + n] = f2bf(v);
          else     ((float*)C)[(size_t)m*ldc + n] = v;
        }
      }
    }
  }
}

// ---------------- in-place silu on z-half of XZbf ----------------
__global__ __launch_bounds__(256) void zsilu_kernel(u16* __restrict__ XZ){
  int idx = blockIdx.x*256 + threadIdx.x;       // R*96 threads, 8 bf16 each
  int row = idx / 96, q = idx % 96;
  u16* p = XZ + (size_t)row*1536 + DINNER + q*8;
  uint4 v = *(uint4*)p;
  unsigned w0=v.x, w1=v.y, w2=v.z, w3=v.w;
  #define ZS(w) { \
    float lo = bf2f((u16)((w) & 0xffffu)); \
    float hi = bf2f((u16)((w) >> 16)); \
    lo = lo / (1.f + __expf(-lo)); \
    hi = hi / (1.f + __expf(-hi)); \
    (w) = (unsigned)f2bf(lo) | ((unsigned)f2bf(hi) << 16); }
  ZS(w0) ZS(w1) ZS(w2) ZS(w3)
  #undef ZS
  v.x=w0; v.y=w1; v.z=w2; v.w=w3;
  *(uint4*)p = v;
}

// ---------------- depthwise causal conv (k=4) + silu, all 4 dirs in one dispatch ----------------
template<int DIR>
__device__ __forceinline__ float conv_acc(const u16* __restrict__ XZ,
    const float* __restrict__ cw, int b, int i, int c, float acc){
  #pragma unroll
  for (int k = 0; k < 4; ++k) {
    int ii = i - 3 + k;
    if (ii >= 0)
      acc += cw[c*4 + k] * bf2f(XZ[((size_t)b*NSEQ + permi<DIR>(ii))*1536 + c]);
  }
  return acc;
}

__global__ __launch_bounds__(256) void conv_silu_all_kernel(const u16* __restrict__ XZ,
    const float* __restrict__ cw, const float* __restrict__ cb,
    u16* __restrict__ UD4, int BS){
  int dir = blockIdx.y;
  int idx = blockIdx.x*256 + threadIdx.x;        // b*1024*768 + i*768 + c
  int c = idx % DINNER;
  int rest = idx / DINNER;
  int i = rest & 1023;
  int b = rest >> 10;
  float acc = cb[c];
  switch (dir) {
    case 0: acc = conv_acc<0>(XZ, cw, b, i, c, acc); break;
    case 1: acc = conv_acc<1>(XZ, cw, b, i, c, acc); break;
    case 2: acc = conv_acc<2>(XZ, cw, b, i, c, acc); break;
    default: acc = conv_acc<3>(XZ, cw, b, i, c, acc); break;
  }
  UD4[((size_t)(dir*BS + b)*NSEQ + i)*1536 + c] = f2bf(acc / (1.f + __expf(-acc)));
}

// ---------------- fused 4-direction selective scan, LDS-accumulated ----------------
template<int CTRL>
__device__ __forceinline__ float dpp_add(float v){
  int t = __builtin_amdgcn_update_dpp(0, __float_as_int(v), CTRL, 0xf, 0xf, true);
  return v + __int_as_float(t);
}
__device__ __forceinline__ float row16_sum(float p){
  p = dpp_add<0x128>(p); // row_ror 8
  p = dpp_add<0x124>(p); // row_ror 4
  p = dpp_add<0x122>(p); // row_ror 2
  p = dpp_add<0x121>(p); // row_ror 1 -> every lane of each 16-row has the row sum
  return p;
}

// Block = 512 thr (8 waves) = 8 channels x 4 dirs. Wave = one dir's 4 channels,
// 16 lanes/channel x 4 states/lane. Rotation-4 prefetch with POINTER INCREMENTS
// (no per-step address recompute): xd ptr += 4*XW, ud ptr += 4*1536 (u at +0,
// dt at +768 imm), z via incremental wave-uniform index. Prefetch overruns are
// read-only and land in adjacent ws buffers (layout guarantees in-bounds).
template<int DIR>
__device__ __forceinline__ void scan_body(
    const u16* __restrict__ xd, const u16* __restrict__ ud,
    const u16* __restrict__ zb,
    u16* __restrict__ ob,        // ABF + b*1024*768 + c0 (block channel base)
    float* __restrict__ lacc,    // LDS [4][SCHUNK][8]
    const float* __restrict__ A_log, const float* __restrict__ Dskip,
    float wgt, int c0w, int grp)
{
  const int lane = threadIdx.x & 63;
  const int g = lane >> 4;            // channel within wave (0..3)
  const int q = lane & 15;            // state quarter: states q*4..q*4+3
  const int c = c0w + g;              // global channel
  const float4 Alq = *(const float4*)(A_log + (size_t)c*DSTATE + q*4);
  const float As0 = -__expf(Alq.x), As1 = -__expf(Alq.y);
  const float As2 = -__expf(Alq.z), As3 = -__expf(Alq.w);
  const float dsk = Dskip[c];
  const u16* zp = zb + DINNER + c;    // + zi*1536
  float* lw = lacc + DIR*SCHUNK*8 + grp*4 + g;   // + (l&127)*8

  // rotation-slot pointers (slot k preloaded with step k)
  const u16* px0 = xd + 0*XW + 24 + q*4;
  const u16* px1 = xd + 1*XW + 24 + q*4;
  const u16* px2 = xd + 2*XW + 24 + q*4;
  const u16* px3 = xd + 3*XW + 24 + q*4;
  const u16* pu0 = ud + 0*1536 + c;
  const u16* pu1 = ud + 1*1536 + c;
  const u16* pu2 = ud + 2*1536 + c;
  const u16* pu3 = ud + 3*1536 + c;
  int zi0 = permi<DIR>(0), zi1 = permi<DIR>(1), zi2 = permi<DIR>(2), zi3 = permi<DIR>(3);

#define SLOAD(k) {                                                          \
    uint2 bd = *(const uint2*)px##k;                                        \
    uint2 cd = *(const uint2*)(px##k + 64);                                 \
    B##k = unp4(bd); C##k = unp4(cd);                                       \
    u##k = bf2f(pu##k[0]); t##k = bf2f(pu##k[768]);                         \
    z##k = bf2f(zp[(ptrdiff_t)zi##k * 1536]);                               \
    px##k += 4*XW; pu##k += 4*1536; zi##k = znext<DIR>(zi##k); }

#define SSTEP(k, l) {                                                       \
    float dtu = t##k * u##k;                                                \
    float e0 = __expf(t##k*As0), e1 = __expf(t##k*As1);                     \
    float e2 = __expf(t##k*As2), e3 = __expf(t##k*As3);                     \
    h0 = e0*h0 + dtu*B##k.x; h1 = e1*h1 + dtu*B##k.y;                       \
    h2 = e2*h2 + dtu*B##k.z; h3 = e3*h3 + dtu*B##k.w;                       \
    float p = h0*C##k.x + h1*C##k.y + h2*C##k.z + h3*C##k.w;                \
    p = row16_sum(p);                                                       \
    float o = wgt*(p + u##k*dsk)*z##k;                                      \
    if (q == 0) lw[((l)&(SCHUNK-1))*8] = o; }

  float4 B0,C0,B1,C1,B2,C2,B3,C3;
  float t0,u0,z0, t1,u1,z1, t2,u2,z2, t3,u3,z3;
  float h0=0.f, h1=0.f, h2=0.f, h3=0.f;
  SLOAD(0) SLOAD(1) SLOAD(2) SLOAD(3)
  __builtin_amdgcn_sched_barrier(0);
  for (int l0 = 0; l0 < NSEQ; l0 += SCHUNK) {
    for (int l = l0; l < l0 + SCHUNK; l += 4) {
      SSTEP(0,l)   SLOAD(0) __builtin_amdgcn_sched_barrier(0);
      SSTEP(1,l+1) SLOAD(1) __builtin_amdgcn_sched_barrier(0);
      SSTEP(2,l+2) SLOAD(2) __builtin_amdgcn_sched_barrier(0);
      SSTEP(3,l+3) SLOAD(3) __builtin_amdgcn_sched_barrier(0);
    }
    __syncthreads();
    // flush: 512 threads, SCHUNK*8 = 1024 outputs, sum 4 dirs, store bf16
    for (int i = threadIdx.x; i < SCHUNK*8; i += 512) {
      float s = lacc[i] + lacc[SCHUNK*8 + i] + lacc[2*SCHUNK*8 + i] + lacc[3*SCHUNK*8 + i];
      int row = i >> 3, cc = i & 7;
      ob[(size_t)(l0 + row)*DINNER + cc] = f2bf(s);
    }
    __syncthreads();
  }
#undef SLOAD
#undef SSTEP
}

__global__ __launch_bounds__(512) void scan_all_kernel(
    const u16* __restrict__ XD4, const u16* __restrict__ UD4,
    const u16* __restrict__ XZ, u16* __restrict__ OB,
    const float* __restrict__ A_log, const float* __restrict__ Dskip,
    const float* __restrict__ WR, int b0, int BS)
{
  __shared__ float lacc[4*SCHUNK*8];
  const int bx = blockIdx.x;                  // 0..95
  const int sx = (bx & 7)*12 + (bx >> 3);     // bijective XCD-chunked swizzle (96=8*12)
  const int c0 = sx * 8;                      // block channel base
  const int b = blockIdx.y;
  const int w = threadIdx.x >> 6;
  const int dir = w & 3;
  const int grp = w >> 2;                     // 0..1
  const int c0w = c0 + grp*4;
  const size_t drb = ((size_t)dir*BS + b) * NSEQ;
  const u16* xd = XD4 + drb*XW;
  const u16* ud = UD4 + drb*1536;
  const u16* zz = XZ  + (size_t)b*NSEQ*1536;
  u16* ob = OB + (size_t)b*NSEQ*DINNER + c0;
  const float wgt = WR[(b0+b)*4 + dir];
  switch (dir) {
    case 0: scan_body<0>(xd, ud, zz, ob, lacc, A_log, Dskip, wgt, c0w, grp); break;
    case 1: scan_body<1>(xd, ud, zz, ob, lacc, A_log, Dskip, wgt, c0w, grp); break;
    case 2: scan_body<2>(xd, ud, zz, ob, lacc, A_log, Dskip, wgt, c0w, grp); break;
    default: scan_body<3>(xd, ud, zz, ob, lacc, A_log, Dskip, wgt, c0w, grp); break;
  }
}

// ---------------- windowed attention (bf16 output) ----------------
__global__ __launch_bounds__(256) void attn_kernel(const float* __restrict__ QKV, u16* __restrict__ O){
  int idx = blockIdx.x*256 + threadIdx.x;
  int tq = idx & 3, h = (idx >> 2) & 3, w = idx >> 4;
  size_t row0 = (size_t)w * 4;
  const float4* qp = (const float4*)(QKV + (row0 + tq)*1152 + h*96);
  float sc[4];
  #pragma unroll
  for (int tk = 0; tk < 4; ++tk) {
    const float4* kp = (const float4*)(QKV + (row0 + tk)*1152 + 384 + h*96);
    float d = 0.f;
    #pragma unroll
    for (int j = 0; j < 24; ++j) {
      float4 qf = qp[j], kf = kp[j];
      d += qf.x*kf.x + qf.y*kf.y + qf.z*kf.z + qf.w*kf.w;
    }
    sc[tk] = d * 0.10206207261596575f;
  }
  float mx = fmaxf(fmaxf(sc[0],sc[1]),fmaxf(sc[2],sc[3]));
  float s = 0.f;
  #pragma unroll
  for (int tk=0;tk<4;++tk){ sc[tk]=__expf(sc[tk]-mx); s+=sc[tk]; }
  float inv = 1.f/s;
  #pragma unroll
  for (int tk=0;tk<4;++tk) sc[tk]*=inv;
  u16* op = O + (row0 + tq)*DMODEL + h*96;
  #pragma unroll 4
  for (int j = 0; j < 24; ++j) {
    float4 o = {0.f,0.f,0.f,0.f};
    #pragma unroll
    for (int tk=0;tk<4;++tk){
      const float4* vp = (const float4*)(QKV + (row0+tk)*1152 + 768 + h*96);
      float4 vf = vp[j];
      o.x += sc[tk]*vf.x; o.y += sc[tk]*vf.y; o.z += sc[tk]*vf.z; o.w += sc[tk]*vf.w;
    }
    ushort4 ov; ov.x=f2bf(o.x); ov.y=f2bf(o.y); ov.z=f2bf(o.z); ov.w=f2bf(o.w);
    *(ushort4*)(op + j*4) = ov;
  }
}

extern "C" void kernel_launch(void* const* d_in, const int* in_sizes, int n_in,
                              void* d_out, int out_size, void* d_ws, size_t ws_size,
                              hipStream_t stream)
{
  (void)in_sizes; (void)n_in; (void)out_size;
  const float* x         = (const float*)d_in[0];
  const float* r_w1      = (const float*)d_in[1];
  const float* r_b1      = (const float*)d_in[2];
  const float* r_w2      = (const float*)d_in[3];
  const float* r_b2      = (const float*)d_in[4];
  const float* ln1_w     = (const float*)d_in[5];
  const float* ln1_b     = (const float*)d_in[6];
  const float* ln2_w     = (const float*)d_in[7];
  const float* ln2_b     = (const float*)d_in[8];
  const float* in_proj_w = (const float*)d_in[9];
  const float* conv_w    = (const float*)d_in[10];
  const float* conv_b    = (const float*)d_in[11];
  const float* x_proj_w  = (const float*)d_in[12];
  const float* dt_proj_w = (const float*)d_in[13];
  const float* dt_proj_b = (const float*)d_in[14];
  const float* A_log     = (const float*)d_in[15];
  const float* D_skip    = (const float*)d_in[16];
  const float* out_proj_w= (const float*)d_in[17];
  const float* qkv_w     = (const float*)d_in[18];
  const float* qkv_b     = (const float*)d_in[19];
  const float* ao_w      = (const float*)d_in[20];
  const float* ao_b      = (const float*)d_in[21];
  const float* gate      = (const float*)d_in[22];
  const float* lng_w     = (const float*)d_in[23];
  const float* lng_b     = (const float*)d_in[24];

  float* ws = (float*)d_ws;
  float* WR = ws;            // 32 floats
  float* G  = ws + 64;       // 3072 floats
  u16*  WBF = (u16*)(ws + 3200);
  u16* ipw = WBF + 0;        // 1536*384
  u16* xpw = WBF + 589824;   // 152*768
  u16* dtw = WBF + 706560;   // 768*24
  u16* opw = WBF + 724992;   // 384*768
  u16* qkw = WBF + 1019904;  // 1152*384
  u16* aow = WBF + 1462272;  // 384*384 (end 1609728 u16 = 804864 fl)

  int BS = 8;
  while (BS > 1) {
    size_t need = ((size_t)808064 + (size_t)BS*1024*5296) * sizeof(float);
    if (need <= ws_size) break;
    BS >>= 1;
  }
  const int R = BS * 1024;

  (void)hipMemsetAsync(ws, 0, 4096*sizeof(float), stream);
  router_mean_kernel<<<dim3(16,8),384,0,stream>>>(x, G);
  router_mlp_kernel<<<8,96,0,stream>>>(G, r_w1, r_b1, r_w2, r_b2, WR);

  cvt4_kernel<<<576,256,0,stream>>>(in_proj_w, ipw, 147456);
  cvt4_kernel<<<114,256,0,stream>>>(x_proj_w,  xpw, 29184);
  cvt4_kernel<<<18,256,0,stream>>>(dt_proj_w,  dtw, 4608);
  cvt4_kernel<<<288,256,0,stream>>>(out_proj_w,opw, 73728);
  cvt4_kernel<<<432,256,0,stream>>>(qkv_w,     qkw, 110592);
  cvt4_kernel<<<144,256,0,stream>>>(ao_w,      aow, 36864);

  // slice buffers (order matters: scan prefetch overruns read into the NEXT buffer)
  float* base = ws + 808064;
  u16*   ABF  = (u16*)base;                        // R*768 u16 (R*384 fl)
  u16*   XZbf = (u16*)(base + (size_t)R*384);      // R*1536 u16 (R*768 fl)
  u16*   UD4  = (u16*)(base + (size_t)R*1152);     // 4R rows x 1536 u16: u | dt (R*3072 fl)
  u16*   XD4  = (u16*)(base + (size_t)R*4224);     // 4R*152 u16 (R*304 fl)
  float* XN2  = base + (size_t)R*4528;             // R*384 f32
  float* AOb  = base + (size_t)R*4912;             // R*384 f32 (end R*5296)
  // post-scan aliases (UD4 region, dead after scan)
  float* X2   = (float*)UD4;                       // R*384 f32
  float* QKV  = (float*)UD4 + (size_t)R*384;       // R*1152 f32
  u16*   ATTO = (u16*)((float*)UD4 + (size_t)R*1536); // R*384 u16

  for (int s = 0; s < 8/BS; ++s) {
    const int b0 = s * BS;
    const size_t xoff = (size_t)b0 * NSEQ * DMODEL;

    ln_bf16out_kernel<<<R/4,256,0,stream>>>(x + xoff, ln1_w, ln1_b, ABF);
    mgemm_kernel<<<dim3(24,R/256),256,0,stream>>>(ABF,384, ipw,384,1536, nullptr,nullptr,0,1, XZbf,1536);
    zsilu_kernel<<<(R*96)/256,256,0,stream>>>(XZbf);
    conv_silu_all_kernel<<<dim3(3*R,4),256,0,stream>>>(XZbf, conv_w, conv_b, UD4, BS);
    // batched over dirs: M = 4R
    mgemm_kernel<<<dim3(3,R/64),256,0,stream>>>(UD4,1536, xpw,768,152, nullptr,nullptr,0,1, XD4,152);
    mgemm_kernel<<<dim3(12,R/64),256,0,stream>>>(XD4,152, dtw,24,768, dt_proj_b,nullptr,1,1, UD4+768,1536);
    scan_all_kernel<<<dim3(96,BS),512,0,stream>>>(XD4, UD4, XZbf, ABF, A_log, D_skip, WR, b0, BS);
    mgemm_kernel<<<dim3(6,R/256),256,0,stream>>>(ABF,768, opw,768,384, nullptr,x + xoff,0,0, X2,384);
    ln_dual_kernel<<<R/4,256,0,stream>>>(X2, ln2_w, ln2_b, XN2, ABF);
    mgemm_kernel<<<dim3(18,R/256),256,0,stream>>>(ABF,384, qkw,384,1152, qkv_b,nullptr,0,0, QKV,1152);
    attn_kernel<<<R/64,256,0,stream>>>(QKV, ATTO);
    mgemm_kernel<<<dim3(6,R/256),256,0,stream>>>(ATTO,384, aow,384,384, ao_b,nullptr,0,0, AOb,384);
    ln_final_kernel<<<R/4,256,0,stream>>>(XN2, AOb, gate, lng_w, lng_b, (float*)d_out + xoff);
  }
}